// Round 1
// baseline (1471.887 us; speedup 1.0000x reference)
//
#include <hip/hip_runtime.h>

#define Bb 64
#define Ss 512
#define INn 1024
#define Ee 128
#define Hh 8
#define Dd 16
#define NLl 4

// ---------------- mask -> lengths (robust to int32/uint8/float32 encoding) ---------
__global__ __launch_bounds__(256) void prep_lengths_kernel(const unsigned char* __restrict__ mask,
                                                           int* __restrict__ lengths) {
    __shared__ int f0, f1, f23;
    if (threadIdx.x == 0) { f0 = 0; f1 = 0; f23 = 0; }
    __syncthreads();
    int l0 = 0, l1 = 0, l23 = 0;
    // scan only first 32768 bytes: safe for every candidate encoding
    for (int i = threadIdx.x; i < Bb * Ss; i += 256) {
        unsigned char v = mask[i];
        if (v) { int m = i & 3; if (m == 0) l0 = 1; else if (m == 1) l1 = 1; else l23 = 1; }
    }
    if (l0) atomicOr(&f0, 1);
    if (l1) atomicOr(&f1, 1);
    if (l23) atomicOr(&f23, 1);
    __syncthreads();
    // int32(0/1): nonzero only at i%4==0. float32(1.0f): nonzero only at i%4==2,3.
    // uint8: nonzero at arbitrary offsets incl. i%4==1 (w.h.p. given random lengths).
    int enc = f1 ? 1 : (f23 ? 2 : 0);  // 1=uint8, 2=float32, 0=int32
    if (threadIdx.x < Bb) {
        int b = threadIdx.x, cnt = 0;
        for (int s = 0; s < Ss; ++s) {
            int idx = b * Ss + s;
            int m;
            if (enc == 1)      m = (mask[idx] != 0);
            else if (enc == 2) m = (((const float*)mask)[idx] != 0.0f);
            else               m = (((const int*)mask)[idx] != 0);
            cnt += (m == 0);
        }
        lengths[b] = cnt;  // mask is monotone per row: valid count == length
    }
}

// ---------------- positional encoding table (S,E) ----------------
__global__ __launch_bounds__(256) void pe_kernel(float* __restrict__ pe) {
    int idx = blockIdx.x * 256 + threadIdx.x;
    if (idx >= Ss * Ee) return;
    int s = idx >> 7, e = idx & 127;
    float expo = (float)(2 * (e >> 1)) * (1.0f / 128.0f);
    float freq = powf(10000.0f, -expo);
    float angle = (float)s * freq;
    pe[idx] = (e & 1) ? cosf(angle) : sinf(angle);
}

// ---------------- h += pe (broadcast over batch) ----------------
__global__ __launch_bounds__(256) void add_pe_kernel(float* __restrict__ h, const float* __restrict__ pe) {
    int i = blockIdx.x * 256 + threadIdx.x;        // over 1048576 float4s
    float4 hv = ((float4*)h)[i];
    float4 pv = ((const float4*)pe)[i & 16383];    // (S*E/4 - 1)
    hv.x += pv.x; hv.y += pv.y; hv.z += pv.z; hv.w += pv.w;
    ((float4*)h)[i] = hv;
}

// ---------------- generic GEMM: C = A(MxK) @ W(KxN) + bias, optional ReLU --------
// tile 64x128, 256 threads, K-chunk 16
template <int RELU>
__global__ __launch_bounds__(256) void gemm_bias_kernel(const float* __restrict__ A,
                                                        const float* __restrict__ W,
                                                        const float* __restrict__ bias,
                                                        float* __restrict__ C,
                                                        int M, int N, int K) {
    __shared__ __align__(16) float As[16][68];   // [kk][row], padded
    __shared__ __align__(16) float Wsh[16][128]; // [kk][col]
    const int tid = threadIdx.x;
    const int tx = tid & 15, ty = tid >> 4;
    const int row0 = blockIdx.x * 64;
    const int col0 = blockIdx.y * 128;
    float acc[4][8];
#pragma unroll
    for (int i = 0; i < 4; ++i)
#pragma unroll
        for (int j = 0; j < 8; ++j) acc[i][j] = 0.0f;

    const int alr = tid >> 2;        // 0..63  (A row in tile)
    const int alk = (tid & 3) * 4;   // 0,4,8,12
    const int wkk = tid >> 4;        // 0..15
    const int wc  = (tid & 15) * 8;  // 0..120

    for (int k0 = 0; k0 < K; k0 += 16) {
        float4 a4 = *(const float4*)&A[(size_t)(row0 + alr) * K + k0 + alk];
        float4 w0 = *(const float4*)&W[(size_t)(k0 + wkk) * N + col0 + wc];
        float4 w1 = *(const float4*)&W[(size_t)(k0 + wkk) * N + col0 + wc + 4];
        As[alk + 0][alr] = a4.x;
        As[alk + 1][alr] = a4.y;
        As[alk + 2][alr] = a4.z;
        As[alk + 3][alr] = a4.w;
        *(float4*)&Wsh[wkk][wc]     = w0;
        *(float4*)&Wsh[wkk][wc + 4] = w1;
        __syncthreads();
#pragma unroll
        for (int kk = 0; kk < 16; ++kk) {
            float4 av = *(const float4*)&As[kk][ty * 4];
            float4 b0 = *(const float4*)&Wsh[kk][tx * 8];
            float4 b1 = *(const float4*)&Wsh[kk][tx * 8 + 4];
            float a_[4] = {av.x, av.y, av.z, av.w};
            float b_[8] = {b0.x, b0.y, b0.z, b0.w, b1.x, b1.y, b1.z, b1.w};
#pragma unroll
            for (int i = 0; i < 4; ++i)
#pragma unroll
                for (int j = 0; j < 8; ++j) acc[i][j] = fmaf(a_[i], b_[j], acc[i][j]);
        }
        __syncthreads();
    }
#pragma unroll
    for (int i = 0; i < 4; ++i) {
        int r = row0 + ty * 4 + i;
#pragma unroll
        for (int j = 0; j < 8; ++j) {
            int c = col0 + tx * 8 + j;
            float v = acc[i][j] + bias[c];
            if (RELU) v = fmaxf(v, 0.0f);
            C[(size_t)r * N + c] = v;
        }
    }
}

// ------------- GEMM (N=128) + bias + residual + LayerNorm fused epilogue ----------
// Hout = LN(A(MxK) @ W(Kx128) + bias + res) ; tile 32x128, 256 threads
__global__ __launch_bounds__(256) void gemm_res_ln_kernel(const float* __restrict__ A,
                                                          const float* __restrict__ W,
                                                          const float* __restrict__ bias,
                                                          const float* __restrict__ res,
                                                          const float* __restrict__ gamma,
                                                          const float* __restrict__ beta,
                                                          float* __restrict__ Hout,
                                                          int K) {
    __shared__ __align__(16) float As[16][36];    // [kk][row]
    __shared__ __align__(16) float Wsh[16][128];
    __shared__ __align__(16) float outs[32][129]; // padded for LN row scans
    __shared__ float mstat[32], rstat[32];
    const int tid = threadIdx.x;
    const int tx = tid & 15, ty = tid >> 4;
    const int row0 = blockIdx.x * 32;
    float acc[2][8];
#pragma unroll
    for (int i = 0; i < 2; ++i)
#pragma unroll
        for (int j = 0; j < 8; ++j) acc[i][j] = 0.0f;

    const int alr = tid >> 3;       // 0..31
    const int alk = (tid & 7) * 2;  // 0..14

    for (int k0 = 0; k0 < K; k0 += 16) {
        float2 a2 = *(const float2*)&A[(size_t)(row0 + alr) * K + k0 + alk];
        // W tile rows k0..k0+15 x all 128 cols is contiguous: 2048 floats
        float4 w0 = *(const float4*)&W[(size_t)k0 * 128 + tid * 8];
        float4 w1 = *(const float4*)&W[(size_t)k0 * 128 + tid * 8 + 4];
        As[alk + 0][alr] = a2.x;
        As[alk + 1][alr] = a2.y;
        ((float4*)Wsh)[tid * 2]     = w0;
        ((float4*)Wsh)[tid * 2 + 1] = w1;
        __syncthreads();
#pragma unroll
        for (int kk = 0; kk < 16; ++kk) {
            float2 av = *(const float2*)&As[kk][ty * 2];
            float4 b0 = *(const float4*)&Wsh[kk][tx * 8];
            float4 b1 = *(const float4*)&Wsh[kk][tx * 8 + 4];
            float a_[2] = {av.x, av.y};
            float b_[8] = {b0.x, b0.y, b0.z, b0.w, b1.x, b1.y, b1.z, b1.w};
#pragma unroll
            for (int i = 0; i < 2; ++i)
#pragma unroll
                for (int j = 0; j < 8; ++j) acc[i][j] = fmaf(a_[i], b_[j], acc[i][j]);
        }
        __syncthreads();
    }
    // epilogue: bias + residual into LDS
#pragma unroll
    for (int i = 0; i < 2; ++i) {
        int r = ty * 2 + i;
        int gr = row0 + r;
#pragma unroll
        for (int j = 0; j < 8; ++j) {
            int c = tx * 8 + j;
            outs[r][c] = acc[i][j] + bias[c] + res[(size_t)gr * 128 + c];
        }
    }
    __syncthreads();
    if (tid < 32) {
        float s = 0.0f, s2 = 0.0f;
#pragma unroll 8
        for (int c = 0; c < 128; ++c) {
            float v = outs[tid][c];
            s += v; s2 += v * v;
        }
        float m = s * (1.0f / 128.0f);
        float var = s2 * (1.0f / 128.0f) - m * m;
        mstat[tid] = m;
        rstat[tid] = rsqrtf(var + 1e-5f);
    }
    __syncthreads();
#pragma unroll
    for (int i = 0; i < 2; ++i) {
        int r = ty * 2 + i;
        int gr = row0 + r;
        float m = mstat[r], rs = rstat[r];
#pragma unroll
        for (int j = 0; j < 8; ++j) {
            int c = tx * 8 + j;
            Hout[(size_t)gr * 128 + c] = (outs[r][c] - m) * rs * gamma[c] + beta[c];
        }
    }
}

// ---------------- batch-axis attention: one wave per (s, head) ----------------
// scores[s,h,i,j] = q[i,s,h,:]·k[j,s,h,:] * 0.25, mask j where s >= len[j]
__global__ __launch_bounds__(64) void attn_kernel(const float* __restrict__ q,
                                                  const float* __restrict__ k,
                                                  const float* __restrict__ v,
                                                  const int* __restrict__ lengths,
                                                  float* __restrict__ o) {
    const int s  = blockIdx.x >> 3;
    const int hh = blockIdx.x & 7;
    const int i  = threadIdx.x;  // query recording index 0..63
    __shared__ __align__(16) float ks[64][16];
    __shared__ __align__(16) float vs[64][16];
    __shared__ int msk[64];

    const size_t base = ((size_t)i * Ss + s) * Ee + hh * Dd;
#pragma unroll
    for (int d4 = 0; d4 < 4; ++d4) {
        ((float4*)ks[i])[d4] = ((const float4*)&k[base])[d4];
        ((float4*)vs[i])[d4] = ((const float4*)&v[base])[d4];
    }
    float qr[16];
#pragma unroll
    for (int d4 = 0; d4 < 4; ++d4) {
        float4 t = ((const float4*)&q[base])[d4];
        qr[d4 * 4 + 0] = t.x; qr[d4 * 4 + 1] = t.y; qr[d4 * 4 + 2] = t.z; qr[d4 * 4 + 3] = t.w;
    }
    msk[i] = (s >= lengths[i]) ? 1 : 0;
    __syncthreads();

    float p[64];
    float mx = -INFINITY;
#pragma unroll
    for (int j = 0; j < 64; ++j) {
        float d = 0.0f;
#pragma unroll
        for (int t = 0; t < 16; ++t) d = fmaf(qr[t], ks[j][t], d);
        d *= 0.25f;                       // 1/sqrt(16)
        p[j] = msk[j] ? -1e30f : d;
        mx = fmaxf(mx, p[j]);
    }
    float sum = 0.0f;
#pragma unroll
    for (int j = 0; j < 64; ++j) {
        p[j] = __expf(p[j] - mx);
        sum += p[j];
    }
    float inv = 1.0f / sum;
    float accv[16];
#pragma unroll
    for (int t = 0; t < 16; ++t) accv[t] = 0.0f;
#pragma unroll
    for (int j = 0; j < 64; ++j) {
        float pj = p[j] * inv;
#pragma unroll
        for (int t = 0; t < 16; ++t) accv[t] = fmaf(pj, vs[j][t], accv[t]);
    }
    float4* op = (float4*)&o[base];
#pragma unroll
    for (int d4 = 0; d4 < 4; ++d4) {
        op[d4] = make_float4(accv[d4 * 4], accv[d4 * 4 + 1], accv[d4 * 4 + 2], accv[d4 * 4 + 3]);
    }
}

// ---------------- masked mean pool over valid positions ----------------
__global__ __launch_bounds__(128) void pool_kernel(const float* __restrict__ h,
                                                   const int* __restrict__ lengths,
                                                   float* __restrict__ meanp) {
    int b = blockIdx.x, e = threadIdx.x;
    int len = lengths[b];
    float s = 0.0f;
    for (int t = 0; t < len; ++t) s += h[((size_t)b * Ss + t) * Ee + e];
    meanp[b * Ee + e] = s / (float)len;
}

// ---------------- tiny classifier head ----------------
__global__ __launch_bounds__(64) void head_kernel(const float* __restrict__ meanp,
                                                  const float* __restrict__ fc1w,
                                                  const float* __restrict__ fc1b,
                                                  const float* __restrict__ fc2w,
                                                  const float* __restrict__ fc2b,
                                                  float* __restrict__ out) {
    int b = blockIdx.x, j = threadIdx.x;
    __shared__ float z[32];
    if (j < 32) {
        float a = fc1b[j];
        for (int e = 0; e < 128; ++e) a = fmaf(meanp[b * 128 + e], fc1w[e * 32 + j], a);
        z[j] = fmaxf(a, 0.0f);
    }
    __syncthreads();
    if (j == 0) {
        float a = fc2b[0];
#pragma unroll
        for (int t = 0; t < 32; ++t) a = fmaf(z[t], fc2w[t], a);
        out[b] = 1.0f / (1.0f + expf(-a));
    }
}

extern "C" void kernel_launch(void* const* d_in, const int* in_sizes, int n_in,
                              void* d_out, int out_size, void* d_ws, size_t ws_size,
                              hipStream_t stream) {
    (void)in_sizes; (void)n_in; (void)out_size; (void)ws_size;
    const float* x        = (const float*)d_in[0];
    const unsigned char* mask = (const unsigned char*)d_in[1];
    const float* embed_w  = (const float*)d_in[2];
    const float* embed_b  = (const float*)d_in[3];
    const float* qkv_w    = (const float*)d_in[4];
    const float* qkv_b    = (const float*)d_in[5];
    const float* out_w    = (const float*)d_in[6];
    const float* out_b    = (const float*)d_in[7];
    const float* ln_g     = (const float*)d_in[8];
    const float* ln_b     = (const float*)d_in[9];
    const float* ff1_w    = (const float*)d_in[10];
    const float* ff1_b    = (const float*)d_in[11];
    const float* ff2_w    = (const float*)d_in[12];
    const float* ff2_b    = (const float*)d_in[13];
    const float* fc1_w    = (const float*)d_in[14];
    const float* fc1_b    = (const float*)d_in[15];
    const float* fc2_w    = (const float*)d_in[16];
    const float* fc2_b    = (const float*)d_in[17];

    float* ws = (float*)d_ws;
    int*   lengths = (int*)ws;            // 64 ints
    float* pe  = ws + 256;                // 65536 floats
    float* h   = ws + 65792;              // 4M floats (B,S,E)
    const size_t BUF = 4194304;
    float* bA = h  + BUF;                 // q  / later: FF intermediate (spans A..D)
    float* bB = bA + BUF;                 // k
    float* bC = bB + BUF;                 // v
    float* bD = bC + BUF;                 // attn out
    float* meanp = bD + BUF;              // 8192 floats

    prep_lengths_kernel<<<1, 256, 0, stream>>>(mask, lengths);
    pe_kernel<<<256, 256, 0, stream>>>(pe);

    // embed: h = x @ embed_w + embed_b
    gemm_bias_kernel<0><<<dim3(512, 1), 256, 0, stream>>>(x, embed_w, embed_b, h, 32768, 128, 1024);

    for (int l = 0; l < NLl; ++l) {
        add_pe_kernel<<<4096, 256, 0, stream>>>(h, pe);
        float* qkvout[3] = {bA, bB, bC};
        for (int t = 0; t < 3; ++t) {
            gemm_bias_kernel<0><<<dim3(512, 1), 256, 0, stream>>>(
                h, qkv_w + (size_t)(l * 3 + t) * 128 * 128, qkv_b + (l * 3 + t) * 128,
                qkvout[t], 32768, 128, 128);
        }
        attn_kernel<<<4096, 64, 0, stream>>>(bA, bB, bC, lengths, bD);
        // h = LN(o @ out_w + out_b + h)
        gemm_res_ln_kernel<<<1024, 256, 0, stream>>>(
            bD, out_w + (size_t)l * 128 * 128, out_b + l * 128,
            h, ln_g + l * 128, ln_b + l * 128, h, 128);
        // t = relu(h @ ff1_w + ff1_b)  (64 MiB across bA..bD, all dead now)
        gemm_bias_kernel<1><<<dim3(512, 4), 256, 0, stream>>>(
            h, ff1_w + (size_t)l * 128 * 512, ff1_b + l * 512, bA, 32768, 512, 128);
        // h = LN(t @ ff2_w + ff2_b + h)
        gemm_res_ln_kernel<<<1024, 256, 0, stream>>>(
            bA, ff2_w + (size_t)l * 512 * 128, ff2_b + l * 128,
            h, ln_g + l * 128, ln_b + l * 128, h, 512);
    }

    pool_kernel<<<64, 128, 0, stream>>>(h, lengths, meanp);
    head_kernel<<<64, 64, 0, stream>>>(meanp, fc1_w, fc1_b, fc2_w, fc2_b, (float*)d_out);
}

// Round 3
// 528.327 us; speedup vs baseline: 2.7859x; 2.7859x over previous
//
#include <hip/hip_runtime.h>

#define Bb 64
#define Ss 512
#define INn 1024
#define Ee 128
#define Hh 8
#define Dd 16
#define NLl 4
#define Mtot (Bb * Ss)  // 32768

typedef unsigned short u16;
typedef __attribute__((ext_vector_type(8))) short short8;
typedef __attribute__((ext_vector_type(4))) float f32x4;

__device__ __forceinline__ float b2f(unsigned u) { return __uint_as_float(u << 16); }
__device__ __forceinline__ u16 f2b(float f) {
    unsigned u = __float_as_uint(f);
    unsigned r = u + 0x7FFFu + ((u >> 16) & 1u);
    return (u16)(r >> 16);
}
__device__ __forceinline__ void up8(uint4 u, float* f) {
    f[0] = b2f(u.x & 0xffffu); f[1] = b2f(u.x >> 16);
    f[2] = b2f(u.y & 0xffffu); f[3] = b2f(u.y >> 16);
    f[4] = b2f(u.z & 0xffffu); f[5] = b2f(u.z >> 16);
    f[6] = b2f(u.w & 0xffffu); f[7] = b2f(u.w >> 16);
}

#define GLOAD_LDS16(g, l) __builtin_amdgcn_global_load_lds( \
    (const __attribute__((address_space(1))) void*)(g),     \
    (__attribute__((address_space(3))) void*)(l), 16, 0, 0)

// ---------------- mask encoding detection + per-recording lengths ----------------
__global__ __launch_bounds__(256) void detect_kernel(const unsigned char* __restrict__ m,
                                                     int* __restrict__ flags) {
    int idx = blockIdx.x * 256 + threadIdx.x;  // 0..2047
    int l0 = 0, l1 = 0, l23 = 0;
    for (int rep = 0; rep < 16; ++rep) {
        int i = idx * 16 + rep;  // first 32768 bytes: safe under all encodings
        if (m[i]) { int md = i & 3; if (md == 0) l0 = 1; else if (md == 1) l1 = 1; else l23 = 1; }
    }
    if (l0) atomicOr(&flags[0], 1);
    if (l1) atomicOr(&flags[1], 1);
    if (l23) atomicOr(&flags[2], 1);
}

__global__ __launch_bounds__(64) void lengths_kernel(const unsigned char* __restrict__ m,
                                                     const int* __restrict__ flags,
                                                     int* __restrict__ lengths) {
    int b = blockIdx.x, t = threadIdx.x;
    // int32(1): nonzero byte only at %4==0. float32(1.0f): only %4 in {2,3}. uint8: %4==1 w.h.p.
    int enc = flags[1] ? 1 : (flags[2] ? 2 : 0);
    int cnt = 0;
    for (int s = t; s < Ss; s += 64) {
        int idx = b * Ss + s;
        int mm;
        if (enc == 1)      mm = (m[idx] != 0);
        else if (enc == 2) mm = (((const float*)(const void*)m)[idx] != 0.0f);
        else               mm = (((const int*)(const void*)m)[idx] != 0);
        cnt += (mm == 0);  // monotone mask: zero count == length
    }
    cnt += __shfl_xor(cnt, 1);  cnt += __shfl_xor(cnt, 2);  cnt += __shfl_xor(cnt, 4);
    cnt += __shfl_xor(cnt, 8);  cnt += __shfl_xor(cnt, 16); cnt += __shfl_xor(cnt, 32);
    if (t == 0) lengths[b] = cnt;
}

// ---------------- positional encoding table (S,E) f32 ----------------
__global__ __launch_bounds__(256) void pe_kernel(float* __restrict__ pe) {
    int idx = blockIdx.x * 256 + threadIdx.x;
    if (idx >= Ss * Ee) return;
    int s = idx >> 7, e = idx & 127;
    float expo = (float)(2 * (e >> 1)) * (1.0f / 128.0f);
    float freq = powf(10000.0f, -expo);
    float angle = (float)s * freq;
    pe[idx] = (e & 1) ? cosf(angle) : sinf(angle);
}

// ---------------- weight prep: fp32 (K,N) -> bf16 transposed (N,K) -------------
__global__ __launch_bounds__(256) void wprep_kernel(const float* __restrict__ ew,
                                                    const float* __restrict__ qw,
                                                    const float* __restrict__ ow,
                                                    const float* __restrict__ f1w,
                                                    const float* __restrict__ f2w,
                                                    u16* __restrict__ we, u16* __restrict__ wq,
                                                    u16* __restrict__ wo, u16* __restrict__ wf1,
                                                    u16* __restrict__ wf2) {
    int idx = blockIdx.x * 256 + threadIdx.x;
    if (idx < 131072) {  // embed: K=1024, N=128
        int k = idx >> 7, n = idx & 127;
        we[n * 1024 + k] = f2b(ew[idx]);
    } else if (idx < 327680) {  // qkv: 12 mats of 128x128 -> per-layer 384xK rows
        int t = idx - 131072; int mat = t >> 14; int r = t & 16383; int k = r >> 7, n = r & 127;
        wq[mat * 16384 + n * 128 + k] = f2b(qw[t]);
    } else if (idx < 393216) {  // out: 4 mats 128x128
        int t = idx - 327680; int mat = t >> 14; int r = t & 16383; int k = r >> 7, n = r & 127;
        wo[mat * 16384 + n * 128 + k] = f2b(ow[t]);
    } else if (idx < 655360) {  // ff1: 4 mats K=128, N=512
        int t = idx - 393216; int mat = t >> 16; int r = t & 65535; int k = r >> 9, n = r & 511;
        wf1[mat * 65536 + n * 128 + k] = f2b(f1w[t]);
    } else if (idx < 917504) {  // ff2: 4 mats K=512, N=128
        int t = idx - 655360; int mat = t >> 16; int r = t & 65535; int k = r >> 7, n = r & 127;
        wf2[mat * 65536 + n * 512 + k] = f2b(f2w[t]);
    }
}

// ---------------- x f32 -> bf16 ----------------
__global__ __launch_bounds__(256) void cvt_x_kernel(const float* __restrict__ x,
                                                    u16* __restrict__ xb) {
    size_t idx = (size_t)blockIdx.x * 256 + threadIdx.x;  // 8 elems each; 4194304 total
    const float4* xp = (const float4*)x;
    float4 a = xp[idx * 2], b = xp[idx * 2 + 1];
    uint4 o;
    o.x = (unsigned)f2b(a.x) | ((unsigned)f2b(a.y) << 16);
    o.y = (unsigned)f2b(a.z) | ((unsigned)f2b(a.w) << 16);
    o.z = (unsigned)f2b(b.x) | ((unsigned)f2b(b.y) << 16);
    o.w = (unsigned)f2b(b.z) | ((unsigned)f2b(b.w) << 16);
    ((uint4*)xb)[idx] = o;
}

// ---------------- h(bf16) += pe(f32), broadcast over batch ----------------
__global__ __launch_bounds__(256) void add_pe_kernel(u16* h, const float* __restrict__ pe) {
    int idx = blockIdx.x * 256 + threadIdx.x;  // 524288 total, 8 bf16 each
    uint4 hv = ((uint4*)h)[idx];
    int r4 = (idx * 2) & 16383;  // float4 index into pe (65536 floats)
    float4 p0 = ((const float4*)pe)[r4];
    float4 p1 = ((const float4*)pe)[r4 + 1];
    float f[8]; up8(hv, f);
    f[0] += p0.x; f[1] += p0.y; f[2] += p0.z; f[3] += p0.w;
    f[4] += p1.x; f[5] += p1.y; f[6] += p1.z; f[7] += p1.w;
    uint4 o;
    o.x = (unsigned)f2b(f[0]) | ((unsigned)f2b(f[1]) << 16);
    o.y = (unsigned)f2b(f[2]) | ((unsigned)f2b(f[3]) << 16);
    o.z = (unsigned)f2b(f[4]) | ((unsigned)f2b(f[5]) << 16);
    o.w = (unsigned)f2b(f[6]) | ((unsigned)f2b(f[7]) << 16);
    ((uint4*)h)[idx] = o;
}

// ---------------- MFMA GEMM: C(bf16) = A(M,K,bf16) @ Wt(N,K,bf16)^T + bias ------
// MI: m-frags per wave (BM = MI*64). EPI: 0=bias(+RELU), 1=bias+res+LayerNorm.
// PERM: output-row permutation. 0: none; 1: r=b*S+s -> s*64+b; 2: r=s*64+b -> b*S+s.
template <int MI, int EPI, int RELU, int PERM>
__global__ __launch_bounds__(256) void gemm_mfma(const u16* __restrict__ A,
                                                 const u16* __restrict__ Wt,
                                                 const float* __restrict__ bias,
                                                 const u16* res,
                                                 const float* __restrict__ gamma,
                                                 const float* __restrict__ beta,
                                                 u16* C, int K, int ldc) {
    __shared__ __align__(16) u16 As[MI * 64 * 64];
    __shared__ __align__(16) u16 Bs[128 * 64];
    const int tid = threadIdx.x;
    const int w = tid >> 6, lane = tid & 63, l16 = lane & 15, lhi = lane >> 4;
    const int row0 = blockIdx.x * (MI * 64), col0 = blockIdx.y * 128;

    f32x4 acc[MI][8];
#pragma unroll
    for (int mi = 0; mi < MI; ++mi)
#pragma unroll
        for (int ni = 0; ni < 8; ++ni) acc[mi][ni] = (f32x4){0.f, 0.f, 0.f, 0.f};

    const int cc8 = (tid & 7) * 8;          // k-subcol within row (elements)
    const int crow = tid >> 3;              // base chunk row
    const u16* Abase = A + (size_t)row0 * K + cc8;
    const u16* Bbase = Wt + (size_t)col0 * K + cc8;
    const int wave_lds = (tid >> 6) * 512;  // ushorts

    for (int k0 = 0; k0 < K; k0 += 64) {
        __syncthreads();
#pragma unroll
        for (int i = 0; i < 2 * MI; ++i)
            GLOAD_LDS16(Abase + (size_t)(i * 32 + crow) * K + k0, &As[i * 2048 + wave_lds]);
#pragma unroll
        for (int i = 0; i < 4; ++i)
            GLOAD_LDS16(Bbase + (size_t)(i * 32 + crow) * K + k0, &Bs[i * 2048 + wave_lds]);
        __syncthreads();
#pragma unroll
        for (int ks = 0; ks < 2; ++ks) {
            short8 af[MI], bfr[8];
#pragma unroll
            for (int mi = 0; mi < MI; ++mi)
                af[mi] = *(const short8*)&As[(w * MI * 16 + mi * 16 + l16) * 64 + ks * 32 + lhi * 8];
#pragma unroll
            for (int ni = 0; ni < 8; ++ni)
                bfr[ni] = *(const short8*)&Bs[(ni * 16 + l16) * 64 + ks * 32 + lhi * 8];
#pragma unroll
            for (int mi = 0; mi < MI; ++mi)
#pragma unroll
                for (int ni = 0; ni < 8; ++ni)
                    acc[mi][ni] = __builtin_amdgcn_mfma_f32_16x16x32_bf16(af[mi], bfr[ni], acc[mi][ni], 0, 0, 0);
        }
    }

    float biasr[8], gr[8], br[8];
#pragma unroll
    for (int ni = 0; ni < 8; ++ni) {
        int c = col0 + ni * 16 + l16;
        biasr[ni] = bias[c];
        if (EPI == 1) { gr[ni] = gamma[c]; br[ni] = beta[c]; }
    }

#pragma unroll
    for (int mi = 0; mi < MI; ++mi) {
#pragma unroll
        for (int reg = 0; reg < 4; ++reg) {
            int r = row0 + w * MI * 16 + mi * 16 + lhi * 4 + reg;
            int orow = (PERM == 1) ? (((r & 511) << 6) + (r >> 9))
                     : (PERM == 2) ? (((r & 63) << 9) + (r >> 6)) : r;
            if (EPI == 0) {
                u16* crw = C + (size_t)orow * ldc + col0;
#pragma unroll
                for (int ni = 0; ni < 8; ++ni) {
                    float v = acc[mi][ni][reg] + biasr[ni];
                    if (RELU) v = fmaxf(v, 0.0f);
                    crw[ni * 16 + l16] = f2b(v);
                }
            } else {
                const u16* rrow = res + (size_t)orow * 128;
                float v[8], s = 0.f, s2 = 0.f;
#pragma unroll
                for (int ni = 0; ni < 8; ++ni) {
                    float x = acc[mi][ni][reg] + biasr[ni] + b2f(rrow[ni * 16 + l16]);
                    v[ni] = x; s += x; s2 += x * x;
                }
                s  += __shfl_xor(s, 1);  s  += __shfl_xor(s, 2);
                s  += __shfl_xor(s, 4);  s  += __shfl_xor(s, 8);
                s2 += __shfl_xor(s2, 1); s2 += __shfl_xor(s2, 2);
                s2 += __shfl_xor(s2, 4); s2 += __shfl_xor(s2, 8);
                float mean = s * (1.0f / 128.0f);
                float var = s2 * (1.0f / 128.0f) - mean * mean;
                float rstd = rsqrtf(fmaxf(var, 0.0f) + 1e-5f);
                u16* crw = C + (size_t)orow * 128;
#pragma unroll
                for (int ni = 0; ni < 8; ++ni)
                    crw[ni * 16 + l16] = f2b((v[ni] - mean) * rstd * gr[ni] + br[ni]);
            }
        }
    }
}

// ---------------- batch-axis attention, (S,B) layout, bf16 ----------------
// qkv rows = s*64+b (stride 384): q @ +0, k @ +128, v @ +256. o rows = s*64+b (stride 128).
__global__ __launch_bounds__(64) void attn_kernel(const u16* __restrict__ qkv,
                                                  const int* __restrict__ lengths,
                                                  u16* __restrict__ o) {
    const int s = blockIdx.x >> 3, hh = blockIdx.x & 7, i = threadIdx.x;
    __shared__ __align__(16) float ks[64][16];
    __shared__ __align__(16) float vs[64][16];
    __shared__ int msk[64];

    const size_t base = ((size_t)(s * 64 + i)) * 384 + hh * 16;
    uint4 qu0 = *(const uint4*)(qkv + base);
    uint4 qu1 = *(const uint4*)(qkv + base + 8);
    uint4 ku0 = *(const uint4*)(qkv + base + 128);
    uint4 ku1 = *(const uint4*)(qkv + base + 136);
    uint4 vu0 = *(const uint4*)(qkv + base + 256);
    uint4 vu1 = *(const uint4*)(qkv + base + 264);
    float qr[16];
    up8(qu0, qr); up8(qu1, qr + 8);
    up8(ku0, ks[i]); up8(ku1, ks[i] + 8);
    up8(vu0, vs[i]); up8(vu1, vs[i] + 8);
    msk[i] = (s >= lengths[i]) ? 1 : 0;
    __syncthreads();

    float p[64];
    float mx = -INFINITY;
#pragma unroll
    for (int j = 0; j < 64; ++j) {
        float d = 0.0f;
#pragma unroll
        for (int t = 0; t < 16; ++t) d = fmaf(qr[t], ks[j][t], d);
        d *= 0.25f;
        p[j] = msk[j] ? -1e30f : d;
        mx = fmaxf(mx, p[j]);
    }
    float sum = 0.0f;
#pragma unroll
    for (int j = 0; j < 64; ++j) { p[j] = __expf(p[j] - mx); sum += p[j]; }
    float inv = 1.0f / sum;
    float accv[16];
#pragma unroll
    for (int t = 0; t < 16; ++t) accv[t] = 0.0f;
#pragma unroll
    for (int j = 0; j < 64; ++j) {
        float pj = p[j] * inv;
#pragma unroll
        for (int t = 0; t < 16; ++t) accv[t] = fmaf(pj, vs[j][t], accv[t]);
    }
    const size_t obase = ((size_t)(s * 64 + i)) * 128 + hh * 16;
    unsigned ou[8];
#pragma unroll
    for (int t = 0; t < 8; ++t)
        ou[t] = (unsigned)f2b(accv[2 * t]) | ((unsigned)f2b(accv[2 * t + 1]) << 16);
    *(uint4*)(o + obase) = make_uint4(ou[0], ou[1], ou[2], ou[3]);
    *(uint4*)(o + obase + 8) = make_uint4(ou[4], ou[5], ou[6], ou[7]);
}

// ---------------- masked mean pool (bf16 h -> f32 meanp) ----------------
__global__ __launch_bounds__(256) void pool_kernel(const u16* __restrict__ h,
                                                   const int* __restrict__ lengths,
                                                   float* __restrict__ meanp) {
    int b = blockIdx.x, e = threadIdx.x & 127, q = threadIdx.x >> 7;
    int len = lengths[b];
    float s = 0.0f;
    for (int t = q; t < len; t += 2) s += b2f(h[((size_t)b * Ss + t) * Ee + e]);
    __shared__ float red[256];
    red[threadIdx.x] = s;
    __syncthreads();
    if (threadIdx.x < 128)
        meanp[b * Ee + threadIdx.x] = (red[threadIdx.x] + red[threadIdx.x + 128]) / (float)len;
}

// ---------------- classifier head ----------------
__global__ __launch_bounds__(64) void head_kernel(const float* __restrict__ meanp,
                                                  const float* __restrict__ fc1w,
                                                  const float* __restrict__ fc1b,
                                                  const float* __restrict__ fc2w,
                                                  const float* __restrict__ fc2b,
                                                  float* __restrict__ out) {
    int b = blockIdx.x, j = threadIdx.x;
    __shared__ float z[32];
    if (j < 32) {
        float a = fc1b[j];
        for (int e = 0; e < 128; ++e) a = fmaf(meanp[b * 128 + e], fc1w[e * 32 + j], a);
        z[j] = fmaxf(a, 0.0f);
    }
    __syncthreads();
    if (j == 0) {
        float a = fc2b[0];
#pragma unroll
        for (int t = 0; t < 32; ++t) a = fmaf(z[t], fc2w[t], a);
        out[b] = 1.0f / (1.0f + expf(-a));
    }
}

extern "C" void kernel_launch(void* const* d_in, const int* in_sizes, int n_in,
                              void* d_out, int out_size, void* d_ws, size_t ws_size,
                              hipStream_t stream) {
    (void)in_sizes; (void)n_in; (void)out_size; (void)ws_size;
    const float* x        = (const float*)d_in[0];
    const unsigned char* mask = (const unsigned char*)d_in[1];
    const float* embed_w  = (const float*)d_in[2];
    const float* embed_b  = (const float*)d_in[3];
    const float* qkv_w    = (const float*)d_in[4];
    const float* qkv_b    = (const float*)d_in[5];
    const float* out_w    = (const float*)d_in[6];
    const float* out_b    = (const float*)d_in[7];
    const float* ln_g     = (const float*)d_in[8];
    const float* ln_b     = (const float*)d_in[9];
    const float* ff1_w    = (const float*)d_in[10];
    const float* ff1_b    = (const float*)d_in[11];
    const float* ff2_w    = (const float*)d_in[12];
    const float* ff2_b    = (const float*)d_in[13];
    const float* fc1_w    = (const float*)d_in[14];
    const float* fc1_b    = (const float*)d_in[15];
    const float* fc2_w    = (const float*)d_in[16];
    const float* fc2_b    = (const float*)d_in[17];

    char* wsb = (char*)d_ws;
    int*   lengths = (int*)wsb;                       // 256 B
    int*   flags   = (int*)(wsb + 256);               // 12 B
    float* pe      = (float*)(wsb + 512);             // 256 KiB -> ends 262656
    u16* wt_embed  = (u16*)(wsb + 262656);            // 262144 B
    u16* wt_qkv    = (u16*)(wsb + 524800);            // 393216 B
    u16* wt_out    = (u16*)(wsb + 918016);            // 131072 B
    u16* wt_ff1    = (u16*)(wsb + 1049088);           // 524288 B
    u16* wt_ff2    = (u16*)(wsb + 1573376);           // 524288 B -> ends 2097664
    u16* hbuf      = (u16*)(wsb + 2097664);           // 8 MiB -> ends 10486272
    char* X0       = wsb + 10486272;                  // 64 MiB region
    u16* xb        = (u16*)X0;                        // 64 MiB (embed input, dead after embed)
    u16* qkvb      = (u16*)X0;                        // 24 MiB   (aliases xb)
    u16* ob        = (u16*)(X0 + 25165824);           // 8 MiB
    u16* tb        = (u16*)(X0 + 33554432);           // 32 MiB -> X ends 67108864
    float* meanp   = (float*)(wsb + 10486272 + 67108864);  // 32 KiB

    hipMemsetAsync(flags, 0, 12, stream);
    detect_kernel<<<8, 256, 0, stream>>>(mask, flags);
    lengths_kernel<<<64, 64, 0, stream>>>(mask, flags, lengths);
    pe_kernel<<<256, 256, 0, stream>>>(pe);
    wprep_kernel<<<3584, 256, 0, stream>>>(embed_w, qkv_w, out_w, ff1_w, ff2_w,
                                           wt_embed, wt_qkv, wt_out, wt_ff1, wt_ff2);
    cvt_x_kernel<<<16384, 256, 0, stream>>>(x, xb);

    // embed: h = xb @ wt_embed^T + embed_b   (BS layout)
    gemm_mfma<1, 0, 0, 0><<<dim3(512, 1), 256, 0, stream>>>(
        xb, wt_embed, embed_b, nullptr, nullptr, nullptr, hbuf, 1024, 128);

    for (int l = 0; l < NLl; ++l) {
        add_pe_kernel<<<2048, 256, 0, stream>>>(hbuf, pe);
        // fused QKV (N=384), store permuted to (S,B) layout
        gemm_mfma<2, 0, 0, 1><<<dim3(256, 3), 256, 0, stream>>>(
            hbuf, wt_qkv + (size_t)l * 49152, qkv_b + l * 384,
            nullptr, nullptr, nullptr, qkvb, 128, 384);
        attn_kernel<<<4096, 64, 0, stream>>>(qkvb, lengths, ob);
        // out-proj + residual + LN, permute rows back to (B,S)
        gemm_mfma<1, 1, 0, 2><<<dim3(512, 1), 256, 0, stream>>>(
            ob, wt_out + (size_t)l * 16384, out_b + l * 128,
            hbuf, ln_g + l * 128, ln_b + l * 128, hbuf, 128, 128);
        // FF1 + ReLU
        gemm_mfma<2, 0, 1, 0><<<dim3(256, 4), 256, 0, stream>>>(
            hbuf, wt_ff1 + (size_t)l * 65536, ff1_b + l * 512,
            nullptr, nullptr, nullptr, tb, 128, 512);
        // FF2 + residual + LN
        gemm_mfma<1, 1, 0, 0><<<dim3(512, 1), 256, 0, stream>>>(
            tb, wt_ff2 + (size_t)l * 65536, ff2_b + l * 128,
            hbuf, ln_g + l * 128, ln_b + l * 128, hbuf, 512, 128);
    }

    pool_kernel<<<64, 256, 0, stream>>>(hbuf, lengths, meanp);
    head_kernel<<<64, 64, 0, stream>>>(meanp, fc1_w, fc1_b, fc2_w, fc2_b, (float*)d_out);
}

// Round 4
// 488.413 us; speedup vs baseline: 3.0136x; 1.0817x over previous
//
#include <hip/hip_runtime.h>

#define Bb 64
#define Ss 512
#define INn 1024
#define Ee 128
#define Hh 8
#define Dd 16
#define NLl 4

typedef unsigned short u16;
typedef __attribute__((ext_vector_type(8))) short short8;
typedef __attribute__((ext_vector_type(4))) float f32x4;

__device__ __forceinline__ float b2f(unsigned u) { return __uint_as_float(u << 16); }
__device__ __forceinline__ u16 f2b(float f) {
    unsigned u = __float_as_uint(f);
    unsigned r = u + 0x7FFFu + ((u >> 16) & 1u);
    return (u16)(r >> 16);
}
__device__ __forceinline__ void up8(uint4 u, float* f) {
    f[0] = b2f(u.x & 0xffffu); f[1] = b2f(u.x >> 16);
    f[2] = b2f(u.y & 0xffffu); f[3] = b2f(u.y >> 16);
    f[4] = b2f(u.z & 0xffffu); f[5] = b2f(u.z >> 16);
    f[6] = b2f(u.w & 0xffffu); f[7] = b2f(u.w >> 16);
}
__device__ __forceinline__ uint2 pk4(float4 f) {
    uint2 r;
    r.x = (unsigned)f2b(f.x) | ((unsigned)f2b(f.y) << 16);
    r.y = (unsigned)f2b(f.z) | ((unsigned)f2b(f.w) << 16);
    return r;
}

#define GLOAD_LDS16(g, l) __builtin_amdgcn_global_load_lds( \
    (const __attribute__((address_space(1))) void*)(g),     \
    (__attribute__((address_space(3))) void*)(l), 16, 0, 0)

// ---------------- mask encoding detection + per-recording lengths ----------------
__global__ __launch_bounds__(256) void detect_kernel(const unsigned char* __restrict__ m,
                                                     int* __restrict__ flags) {
    int idx = blockIdx.x * 256 + threadIdx.x;  // 0..2047
    int l0 = 0, l1 = 0, l23 = 0;
    for (int rep = 0; rep < 16; ++rep) {
        int i = idx * 16 + rep;  // first 32768 bytes: safe under all encodings
        if (m[i]) { int md = i & 3; if (md == 0) l0 = 1; else if (md == 1) l1 = 1; else l23 = 1; }
    }
    if (l0) atomicOr(&flags[0], 1);
    if (l1) atomicOr(&flags[1], 1);
    if (l23) atomicOr(&flags[2], 1);
}

__global__ __launch_bounds__(64) void lengths_kernel(const unsigned char* __restrict__ m,
                                                     const int* __restrict__ flags,
                                                     int* __restrict__ lengths) {
    int b = blockIdx.x, t = threadIdx.x;
    int enc = flags[1] ? 1 : (flags[2] ? 2 : 0);  // 1=uint8, 2=float32, 0=int32
    int cnt = 0;
    for (int s = t; s < Ss; s += 64) {
        int idx = b * Ss + s;
        int mm;
        if (enc == 1)      mm = (m[idx] != 0);
        else if (enc == 2) mm = (((const float*)(const void*)m)[idx] != 0.0f);
        else               mm = (((const int*)(const void*)m)[idx] != 0);
        cnt += (mm == 0);  // monotone mask: zero count == length
    }
    cnt += __shfl_xor(cnt, 1);  cnt += __shfl_xor(cnt, 2);  cnt += __shfl_xor(cnt, 4);
    cnt += __shfl_xor(cnt, 8);  cnt += __shfl_xor(cnt, 16); cnt += __shfl_xor(cnt, 32);
    if (t == 0) lengths[b] = cnt;
}

// ---------------- positional encoding table (S,E) f32 ----------------
__global__ __launch_bounds__(256) void pe_kernel(float* __restrict__ pe) {
    int idx = blockIdx.x * 256 + threadIdx.x;
    if (idx >= Ss * Ee) return;
    int s = idx >> 7, e = idx & 127;
    float expo = (float)(2 * (e >> 1)) * (1.0f / 128.0f);
    float freq = powf(10000.0f, -expo);
    float angle = (float)s * freq;
    pe[idx] = (e & 1) ? cosf(angle) : sinf(angle);
}

// ------------- weight prep: tiled transpose-convert f32 (K,N) -> bf16 (N,K) -------
// 224 blocks, one 64x64 tile each; coalesced reads AND writes via LDS.
__global__ __launch_bounds__(256) void wprep_kernel(const float* __restrict__ ew,
                                                    const float* __restrict__ qw,
                                                    const float* __restrict__ ow,
                                                    const float* __restrict__ f1w,
                                                    const float* __restrict__ f2w,
                                                    u16* __restrict__ we, u16* __restrict__ wq,
                                                    u16* __restrict__ wo, u16* __restrict__ wf1,
                                                    u16* __restrict__ wf2) {
    int bid = blockIdx.x;
    const float* src; u16* dst; int K, N, tile;
    if (bid < 32)       { src = ew;  dst = we;  K = 1024; N = 128; tile = bid; }
    else if (bid < 80)  { int b = bid - 32;  int mat = b >> 2; src = qw  + (size_t)mat * 16384; dst = wq  + (size_t)mat * 16384; K = 128; N = 128; tile = b & 3; }
    else if (bid < 96)  { int b = bid - 80;  int mat = b >> 2; src = ow  + (size_t)mat * 16384; dst = wo  + (size_t)mat * 16384; K = 128; N = 128; tile = b & 3; }
    else if (bid < 160) { int b = bid - 96;  int mat = b >> 4; src = f1w + (size_t)mat * 65536; dst = wf1 + (size_t)mat * 65536; K = 128; N = 512; tile = b & 15; }
    else                { int b = bid - 160; int mat = b >> 4; src = f2w + (size_t)mat * 65536; dst = wf2 + (size_t)mat * 65536; K = 512; N = 128; tile = b & 15; }
    int ktiles = K >> 6;
    int k0 = (tile % ktiles) * 64, n0 = (tile / ktiles) * 64;
    __shared__ __align__(16) u16 t_s[64 * 68];
    int r = threadIdx.x >> 2, cq = (threadIdx.x & 3) * 16;
    const float* sp = src + (size_t)(k0 + r) * N + n0 + cq;
#pragma unroll
    for (int i = 0; i < 4; ++i) {
        float4 f = *(const float4*)(sp + 4 * i);
        *(uint2*)&t_s[r * 68 + cq + 4 * i] = pk4(f);
    }
    __syncthreads();
    u16 tmp[16];
#pragma unroll
    for (int kk = 0; kk < 16; ++kk) tmp[kk] = t_s[(cq + kk) * 68 + r];
    u16* dp = dst + (size_t)(n0 + r) * K + k0 + cq;
    *(uint4*)dp       = ((uint4*)tmp)[0];
    *(uint4*)(dp + 8) = ((uint4*)tmp)[1];
}

// ---------------- embed GEMM: h = x(f32) @ wt_embed^T + bias + pe ----------------
// BM=64, N=128, K=1024. A reg-staged (f32->bf16) into padded LDS; B via gload_lds.
__global__ __launch_bounds__(256) void embed_gemm(const float* __restrict__ X,
                                                  const u16* __restrict__ Wt,
                                                  const float* __restrict__ bias,
                                                  const float* __restrict__ pe,
                                                  u16* __restrict__ C) {
    __shared__ __align__(16) u16 Af[64 * 68];
    __shared__ __align__(16) u16 Bs[128 * 64];
    const int tid = threadIdx.x;
    const int w = tid >> 6, lane = tid & 63, l16 = lane & 15, lhi = lane >> 4;
    const int row0 = blockIdx.x * 64;
    f32x4 acc[8];
#pragma unroll
    for (int ni = 0; ni < 8; ++ni) acc[ni] = (f32x4){0.f, 0.f, 0.f, 0.f};

    const int ar = tid >> 2, ak = (tid & 3) * 16;
    const int crow = tid >> 3, cc8 = (tid & 7) * 8;
    const int wave_lds = w * 512;
    const u16* Bbase = Wt + cc8;
    const float* Arow = X + (size_t)(row0 + ar) * 1024 + ak;

    for (int k0 = 0; k0 < 1024; k0 += 64) {
        __syncthreads();
#pragma unroll
        for (int i = 0; i < 4; ++i)
            GLOAD_LDS16(Bbase + (size_t)(i * 32 + crow) * 1024 + k0, &Bs[i * 2048 + wave_lds]);
#pragma unroll
        for (int i = 0; i < 4; ++i) {
            float4 f = *(const float4*)(Arow + k0 + 4 * i);
            *(uint2*)&Af[ar * 68 + ak + 4 * i] = pk4(f);
        }
        __syncthreads();
#pragma unroll
        for (int ks = 0; ks < 2; ++ks) {
            short8 af;
            ((uint2*)&af)[0] = *(const uint2*)&Af[(w * 16 + l16) * 68 + ks * 32 + lhi * 8];
            ((uint2*)&af)[1] = *(const uint2*)&Af[(w * 16 + l16) * 68 + ks * 32 + lhi * 8 + 4];
#pragma unroll
            for (int ni = 0; ni < 8; ++ni) {
                short8 bfr = *(const short8*)&Bs[(ni * 16 + l16) * 64 + ks * 32 + lhi * 8];
                acc[ni] = __builtin_amdgcn_mfma_f32_16x16x32_bf16(af, bfr, acc[ni], 0, 0, 0);
            }
        }
    }
    float biasr[8];
#pragma unroll
    for (int ni = 0; ni < 8; ++ni) biasr[ni] = bias[ni * 16 + l16];
#pragma unroll
    for (int reg = 0; reg < 4; ++reg) {
        int r = row0 + w * 16 + lhi * 4 + reg;
        const float* per = pe + (size_t)(r & 511) * 128;
        u16* crw = C + (size_t)r * 128;
#pragma unroll
        for (int ni = 0; ni < 8; ++ni) {
            int c = ni * 16 + l16;
            crw[c] = f2b(acc[ni][reg] + biasr[ni] + per[c]);
        }
    }
}

// ---------------- MFMA GEMM: C(bf16) = A(M,K,bf16) @ Wt(N,K,bf16)^T + bias ------
// MI: m-frags/wave (BM=MI*64). EPI: 0=bias(+RELU), 1=bias+res+LayerNorm(+pe).
// PERM: 0 none; 1: row r=b*S+s -> s*64+b. SPLIT: QKV split output (Q | KV).
template <int MI, int EPI, int RELU, int PERM, int SPLIT>
__global__ __launch_bounds__(256) void gemm_mfma(const u16* __restrict__ A,
                                                 const u16* __restrict__ Wt,
                                                 const float* __restrict__ bias,
                                                 const u16* res,
                                                 const float* __restrict__ gamma,
                                                 const float* __restrict__ beta,
                                                 const float* __restrict__ pe,
                                                 u16* C, u16* C2, int K, int ldc) {
    __shared__ __align__(16) u16 As[MI * 64 * 64];
    __shared__ __align__(16) u16 Bs[128 * 64];
    const int tid = threadIdx.x;
    const int w = tid >> 6, lane = tid & 63, l16 = lane & 15, lhi = lane >> 4;
    const int row0 = blockIdx.x * (MI * 64), col0 = blockIdx.y * 128;

    f32x4 acc[MI][8];
#pragma unroll
    for (int mi = 0; mi < MI; ++mi)
#pragma unroll
        for (int ni = 0; ni < 8; ++ni) acc[mi][ni] = (f32x4){0.f, 0.f, 0.f, 0.f};

    const int cc8 = (tid & 7) * 8;
    const int crow = tid >> 3;
    const u16* Abase = A + (size_t)row0 * K + cc8;
    const u16* Bbase = Wt + (size_t)col0 * K + cc8;
    const int wave_lds = w * 512;

    for (int k0 = 0; k0 < K; k0 += 64) {
        __syncthreads();
#pragma unroll
        for (int i = 0; i < 2 * MI; ++i)
            GLOAD_LDS16(Abase + (size_t)(i * 32 + crow) * K + k0, &As[i * 2048 + wave_lds]);
#pragma unroll
        for (int i = 0; i < 4; ++i)
            GLOAD_LDS16(Bbase + (size_t)(i * 32 + crow) * K + k0, &Bs[i * 2048 + wave_lds]);
        __syncthreads();
#pragma unroll
        for (int ks = 0; ks < 2; ++ks) {
            short8 af[MI], bfr[8];
#pragma unroll
            for (int mi = 0; mi < MI; ++mi)
                af[mi] = *(const short8*)&As[(w * MI * 16 + mi * 16 + l16) * 64 + ks * 32 + lhi * 8];
#pragma unroll
            for (int ni = 0; ni < 8; ++ni)
                bfr[ni] = *(const short8*)&Bs[(ni * 16 + l16) * 64 + ks * 32 + lhi * 8];
#pragma unroll
            for (int mi = 0; mi < MI; ++mi)
#pragma unroll
                for (int ni = 0; ni < 8; ++ni)
                    acc[mi][ni] = __builtin_amdgcn_mfma_f32_16x16x32_bf16(af[mi], bfr[ni], acc[mi][ni], 0, 0, 0);
        }
    }

    float biasr[8], gr[8], br[8];
#pragma unroll
    for (int ni = 0; ni < 8; ++ni) {
        int c = col0 + ni * 16 + l16;
        biasr[ni] = bias[c];
        if (EPI == 1) { gr[ni] = gamma[c]; br[ni] = beta[c]; }
    }

#pragma unroll
    for (int mi = 0; mi < MI; ++mi) {
#pragma unroll
        for (int reg = 0; reg < 4; ++reg) {
            int r = row0 + w * MI * 16 + mi * 16 + lhi * 4 + reg;
            int orow = (PERM == 1) ? (((r & 511) << 6) + (r >> 9)) : r;
            if (EPI == 0) {
                u16* crw;
                int cbase;
                if (SPLIT) {
                    if (col0 == 0) { crw = C + (size_t)orow * 128; cbase = 0; }
                    else           { crw = C2 + (size_t)orow * 256; cbase = col0 - 128; }
                } else {
                    crw = C + (size_t)orow * ldc; cbase = col0;
                }
#pragma unroll
                for (int ni = 0; ni < 8; ++ni) {
                    float v = acc[mi][ni][reg] + biasr[ni];
                    if (RELU) v = fmaxf(v, 0.0f);
                    crw[cbase + ni * 16 + l16] = f2b(v);
                }
            } else {
                const u16* rrow = res + (size_t)orow * 128;
                float v[8], s = 0.f, s2 = 0.f;
#pragma unroll
                for (int ni = 0; ni < 8; ++ni) {
                    float x = acc[mi][ni][reg] + biasr[ni] + b2f(rrow[ni * 16 + l16]);
                    v[ni] = x; s += x; s2 += x * x;
                }
                s  += __shfl_xor(s, 1);  s  += __shfl_xor(s, 2);
                s  += __shfl_xor(s, 4);  s  += __shfl_xor(s, 8);
                s2 += __shfl_xor(s2, 1); s2 += __shfl_xor(s2, 2);
                s2 += __shfl_xor(s2, 4); s2 += __shfl_xor(s2, 8);
                float mean = s * (1.0f / 128.0f);
                float var = s2 * (1.0f / 128.0f) - mean * mean;
                float rstd = rsqrtf(fmaxf(var, 0.0f) + 1e-5f);
                u16* crw = C + (size_t)orow * 128;
#pragma unroll
                for (int ni = 0; ni < 8; ++ni) {
                    float val = (v[ni] - mean) * rstd * gr[ni] + br[ni];
                    if (pe) val += pe[(size_t)(orow & 511) * 128 + ni * 16 + l16];
                    crw[ni * 16 + l16] = f2b(val);
                }
            }
        }
    }
}

// ------- fused batch-axis attention + out-proj + residual + LN, one block per s ----
// kvb rows s*64+b (256 wide: K|V); qb rows s*64+b (128 wide). h in-out (B,S) rows.
__global__ __launch_bounds__(256) void attnout_kernel(const u16* __restrict__ qb,
                                                      const u16* __restrict__ kvb,
                                                      const u16* __restrict__ wo,
                                                      const float* __restrict__ outb,
                                                      const int* __restrict__ lengths,
                                                      const float* __restrict__ gamma,
                                                      const float* __restrict__ beta,
                                                      u16* __restrict__ h) {
    const int s = blockIdx.x;
    const int tid = threadIdx.x, w = tid >> 6, lane = tid & 63;
    const int l16 = lane & 15, lhi = lane >> 4;
    __shared__ __align__(16) u16 kv_s[64 * 256];   // 32 KB
    __shared__ __align__(16) u16 o_s[64 * 132];    // 16.5 KB (pad 4)
    __shared__ __align__(16) u16 res_s[64 * 128];  // 16 KB
    __shared__ int len_s[64];

    {
        const u16* src = kvb + (size_t)s * 16384;
#pragma unroll
        for (int i = 0; i < 8; ++i)
            GLOAD_LDS16(src + i * 2048 + w * 512 + lane * 8, &kv_s[i * 2048 + w * 512]);
#pragma unroll
        for (int i = 0; i < 4; ++i) {
            int slot = i * 2048 + w * 512 + lane * 8;
            int row = slot >> 7, col = slot & 127;
            GLOAD_LDS16(h + ((size_t)row * 512 + s) * 128 + col, &res_s[i * 2048 + w * 512]);
        }
    }
    if (tid < 64) len_s[tid] = lengths[tid];
    __syncthreads();

    // attention: wave w handles heads 2w, 2w+1; lane = query recording b
#pragma unroll
    for (int hp = 0; hp < 2; ++hp) {
        const int hh = w * 2 + hp;
        const u16* qrow = qb + ((size_t)(s * 64 + lane)) * 128 + hh * 16;
        uint4 q0 = *(const uint4*)qrow, q1 = *(const uint4*)(qrow + 8);
        float qr[16]; up8(q0, qr); up8(q1, qr + 8);
        float p[64];
        float mx = -INFINITY;
#pragma unroll
        for (int j = 0; j < 64; ++j) {
            const u16* kr = &kv_s[j * 256 + hh * 16];
            uint4 k0 = *(const uint4*)kr, k1 = *(const uint4*)(kr + 8);
            float kf[16]; up8(k0, kf); up8(k1, kf + 8);
            float d = 0.f;
#pragma unroll
            for (int t = 0; t < 16; ++t) d = fmaf(qr[t], kf[t], d);
            d *= 0.25f;
            p[j] = (s >= len_s[j]) ? -1e30f : d;
            mx = fmaxf(mx, p[j]);
        }
        float sum = 0.f;
#pragma unroll
        for (int j = 0; j < 64; ++j) { p[j] = __expf(p[j] - mx); sum += p[j]; }
        float inv = 1.0f / sum;
        float accv[16];
#pragma unroll
        for (int t = 0; t < 16; ++t) accv[t] = 0.f;
#pragma unroll
        for (int j = 0; j < 64; ++j) {
            const u16* vr = &kv_s[j * 256 + 128 + hh * 16];
            uint4 v0 = *(const uint4*)vr, v1 = *(const uint4*)(vr + 8);
            float vf[16]; up8(v0, vf); up8(v1, vf + 8);
            float pj = p[j] * inv;
#pragma unroll
            for (int t = 0; t < 16; ++t) accv[t] = fmaf(pj, vf[t], accv[t]);
        }
        u16* orow_p = &o_s[lane * 132 + hh * 16];
#pragma unroll
        for (int t = 0; t < 4; ++t) {
            uint2 u;
            u.x = (unsigned)f2b(accv[4 * t + 0]) | ((unsigned)f2b(accv[4 * t + 1]) << 16);
            u.y = (unsigned)f2b(accv[4 * t + 2]) | ((unsigned)f2b(accv[4 * t + 3]) << 16);
            *(uint2*)(orow_p + 4 * t) = u;
        }
    }
    __syncthreads();

    // out-proj: o(64x128) @ wo^T(128x128), wave w does rows w*16..w*16+15
    f32x4 acc[8];
#pragma unroll
    for (int ni = 0; ni < 8; ++ni) acc[ni] = (f32x4){0.f, 0.f, 0.f, 0.f};
#pragma unroll
    for (int ks = 0; ks < 4; ++ks) {
        short8 af;
        const int abase = (w * 16 + l16) * 132 + ks * 32 + lhi * 8;
        ((uint2*)&af)[0] = *(const uint2*)&o_s[abase];
        ((uint2*)&af)[1] = *(const uint2*)&o_s[abase + 4];
#pragma unroll
        for (int ni = 0; ni < 8; ++ni) {
            short8 bfr = *(const short8*)(wo + (size_t)(ni * 16 + l16) * 128 + ks * 32 + lhi * 8);
            acc[ni] = __builtin_amdgcn_mfma_f32_16x16x32_bf16(af, bfr, acc[ni], 0, 0, 0);
        }
    }

    float biasr[8], gr[8], br[8];
#pragma unroll
    for (int ni = 0; ni < 8; ++ni) {
        int c = ni * 16 + l16;
        biasr[ni] = outb[c]; gr[ni] = gamma[c]; br[ni] = beta[c];
    }
#pragma unroll
    for (int reg = 0; reg < 4; ++reg) {
        int row = w * 16 + lhi * 4 + reg;
        float v[8], sm = 0.f, s2 = 0.f;
#pragma unroll
        for (int ni = 0; ni < 8; ++ni) {
            float x = acc[ni][reg] + biasr[ni] + b2f(res_s[row * 128 + ni * 16 + l16]);
            v[ni] = x; sm += x; s2 += x * x;
        }
        sm += __shfl_xor(sm, 1); sm += __shfl_xor(sm, 2);
        sm += __shfl_xor(sm, 4); sm += __shfl_xor(sm, 8);
        s2 += __shfl_xor(s2, 1); s2 += __shfl_xor(s2, 2);
        s2 += __shfl_xor(s2, 4); s2 += __shfl_xor(s2, 8);
        float mean = sm * (1.0f / 128.0f);
        float var = s2 * (1.0f / 128.0f) - mean * mean;
        float rstd = rsqrtf(fmaxf(var, 0.0f) + 1e-5f);
#pragma unroll
        for (int ni = 0; ni < 8; ++ni)
            res_s[row * 128 + ni * 16 + l16] = f2b((v[ni] - mean) * rstd * gr[ni] + br[ni]);
    }
    __syncthreads();
    {
        int row = tid >> 2, ch = (tid & 3) * 32;
        u16* dst = h + ((size_t)row * 512 + s) * 128 + ch;
        const u16* srcp = &res_s[row * 128 + ch];
#pragma unroll
        for (int i = 0; i < 4; ++i)
            *(uint4*)(dst + 8 * i) = *(const uint4*)(srcp + 8 * i);
    }
}

// ---------------- masked mean pool (bf16 h -> f32 meanp) ----------------
__global__ __launch_bounds__(256) void pool_kernel(const u16* __restrict__ h,
                                                   const int* __restrict__ lengths,
                                                   float* __restrict__ meanp) {
    int b = blockIdx.x, e = threadIdx.x & 127, q = threadIdx.x >> 7;
    int len = lengths[b];
    float s = 0.0f;
    for (int t = q; t < len; t += 2) s += b2f(h[((size_t)b * Ss + t) * Ee + e]);
    __shared__ float red[256];
    red[threadIdx.x] = s;
    __syncthreads();
    if (threadIdx.x < 128)
        meanp[b * Ee + threadIdx.x] = (red[threadIdx.x] + red[threadIdx.x + 128]) / (float)len;
}

// ---------------- classifier head ----------------
__global__ __launch_bounds__(64) void head_kernel(const float* __restrict__ meanp,
                                                  const float* __restrict__ fc1w,
                                                  const float* __restrict__ fc1b,
                                                  const float* __restrict__ fc2w,
                                                  const float* __restrict__ fc2b,
                                                  float* __restrict__ out) {
    int b = blockIdx.x, j = threadIdx.x;
    __shared__ float z[32];
    if (j < 32) {
        float a = fc1b[j];
        for (int e = 0; e < 128; ++e) a = fmaf(meanp[b * 128 + e], fc1w[e * 32 + j], a);
        z[j] = fmaxf(a, 0.0f);
    }
    __syncthreads();
    if (j == 0) {
        float a = fc2b[0];
#pragma unroll
        for (int t = 0; t < 32; ++t) a = fmaf(z[t], fc2w[t], a);
        out[b] = 1.0f / (1.0f + expf(-a));
    }
}

extern "C" void kernel_launch(void* const* d_in, const int* in_sizes, int n_in,
                              void* d_out, int out_size, void* d_ws, size_t ws_size,
                              hipStream_t stream) {
    (void)in_sizes; (void)n_in; (void)out_size; (void)ws_size;
    const float* x        = (const float*)d_in[0];
    const unsigned char* mask = (const unsigned char*)d_in[1];
    const float* embed_w  = (const float*)d_in[2];
    const float* embed_b  = (const float*)d_in[3];
    const float* qkv_w    = (const float*)d_in[4];
    const float* qkv_b    = (const float*)d_in[5];
    const float* out_w    = (const float*)d_in[6];
    const float* out_b    = (const float*)d_in[7];
    const float* ln_g     = (const float*)d_in[8];
    const float* ln_b     = (const float*)d_in[9];
    const float* ff1_w    = (const float*)d_in[10];
    const float* ff1_b    = (const float*)d_in[11];
    const float* ff2_w    = (const float*)d_in[12];
    const float* ff2_b    = (const float*)d_in[13];
    const float* fc1_w    = (const float*)d_in[14];
    const float* fc1_b    = (const float*)d_in[15];
    const float* fc2_w    = (const float*)d_in[16];
    const float* fc2_b    = (const float*)d_in[17];

    char* wsb = (char*)d_ws;
    int*   lengths = (int*)wsb;                  // 256 B
    int*   flags   = (int*)(wsb + 256);          // 256 B
    float* pe      = (float*)(wsb + 512);        // 256 KiB -> 262656
    u16* wt_embed  = (u16*)(wsb + 262656);       // 256 KiB -> 524800
    u16* wt_qkv    = (u16*)(wsb + 524800);       // 384 KiB -> 918016
    u16* wt_out    = (u16*)(wsb + 918016);       // 128 KiB -> 1049088
    u16* wt_ff1    = (u16*)(wsb + 1049088);      // 512 KiB -> 1573376
    u16* wt_ff2    = (u16*)(wsb + 1573376);      // 512 KiB -> 2097664
    u16* hbuf      = (u16*)(wsb + 2097664);      // 8 MiB  -> 10486272
    u16* qb        = (u16*)(wsb + 10486272);     // 8 MiB  -> 18874880
    u16* kvb       = (u16*)(wsb + 18874880);     // 16 MiB -> 35652096
    u16* tb        = (u16*)(wsb + 35652096);     // 32 MiB -> 69206528
    float* meanp   = (float*)(wsb + 69206528);   // 32 KiB

    hipMemsetAsync(flags, 0, 12, stream);
    detect_kernel<<<8, 256, 0, stream>>>(mask, flags);
    lengths_kernel<<<64, 64, 0, stream>>>(mask, flags, lengths);
    pe_kernel<<<256, 256, 0, stream>>>(pe);
    wprep_kernel<<<224, 256, 0, stream>>>(embed_w, qkv_w, out_w, ff1_w, ff2_w,
                                          wt_embed, wt_qkv, wt_out, wt_ff1, wt_ff2);

    // embed: h = x @ embed_w + b + pe   (B,S) rows
    embed_gemm<<<512, 256, 0, stream>>>(x, wt_embed, embed_b, pe, hbuf);

    for (int l = 0; l < NLl; ++l) {
        // fused QKV (N=384), permuted rows s*64+b, split into Q | KV buffers
        gemm_mfma<2, 0, 0, 1, 1><<<dim3(256, 3), 256, 0, stream>>>(
            hbuf, wt_qkv + (size_t)l * 49152, qkv_b + l * 384,
            nullptr, nullptr, nullptr, nullptr, qb, kvb, 128, 0);
        // attention + out-proj + residual + LN (in-place on hbuf)
        attnout_kernel<<<512, 256, 0, stream>>>(
            qb, kvb, wt_out + (size_t)l * 16384, out_b + l * 128,
            lengths, ln_g + l * 128, ln_b + l * 128, hbuf);
        // FF1 + ReLU
        gemm_mfma<2, 0, 1, 0, 0><<<dim3(256, 4), 256, 0, stream>>>(
            hbuf, wt_ff1 + (size_t)l * 65536, ff1_b + l * 512,
            nullptr, nullptr, nullptr, nullptr, tb, nullptr, 128, 512);
        // FF2 + residual + LN (+pe for next layer, except after last layer)
        gemm_mfma<1, 1, 0, 0, 0><<<dim3(512, 1), 256, 0, stream>>>(
            tb, wt_ff2 + (size_t)l * 65536, ff2_b + l * 128,
            hbuf, ln_g + l * 128, ln_b + l * 128, (l < 3) ? pe : nullptr,
            hbuf, nullptr, 512, 128);
    }

    pool_kernel<<<64, 256, 0, stream>>>(hbuf, lengths, meanp);
    head_kernel<<<64, 64, 0, stream>>>(meanp, fc1_w, fc1_b, fc2_w, fc2_b, (float*)d_out);
}

// Round 5
// 446.190 us; speedup vs baseline: 3.2988x; 1.0946x over previous
//
#include <hip/hip_runtime.h>

#define Bb 64
#define Ss 512
#define INn 1024
#define Ee 128
#define Hh 8
#define Dd 16
#define NLl 4

typedef unsigned short u16;
typedef __attribute__((ext_vector_type(8))) short short8;
typedef __attribute__((ext_vector_type(4))) float f32x4;

__device__ __forceinline__ float b2f(unsigned u) { return __uint_as_float(u << 16); }
__device__ __forceinline__ u16 f2b(float f) {
    unsigned u = __float_as_uint(f);
    unsigned r = u + 0x7FFFu + ((u >> 16) & 1u);
    return (u16)(r >> 16);
}
__device__ __forceinline__ void up8(uint4 u, float* f) {
    f[0] = b2f(u.x & 0xffffu); f[1] = b2f(u.x >> 16);
    f[2] = b2f(u.y & 0xffffu); f[3] = b2f(u.y >> 16);
    f[4] = b2f(u.z & 0xffffu); f[5] = b2f(u.z >> 16);
    f[6] = b2f(u.w & 0xffffu); f[7] = b2f(u.w >> 16);
}
__device__ __forceinline__ uint2 pk4(float4 f) {
    uint2 r;
    r.x = (unsigned)f2b(f.x) | ((unsigned)f2b(f.y) << 16);
    r.y = (unsigned)f2b(f.z) | ((unsigned)f2b(f.w) << 16);
    return r;
}

#define GLOAD_LDS16(g, l) __builtin_amdgcn_global_load_lds( \
    (const __attribute__((address_space(1))) void*)(g),     \
    (__attribute__((address_space(3))) void*)(l), 16, 0, 0)

// ---------------- mask encoding detection + per-recording lengths ----------------
__global__ __launch_bounds__(256) void detect_kernel(const unsigned char* __restrict__ m,
                                                     int* __restrict__ flags) {
    int idx = blockIdx.x * 256 + threadIdx.x;  // 0..2047
    int l0 = 0, l1 = 0, l23 = 0;
    for (int rep = 0; rep < 16; ++rep) {
        int i = idx * 16 + rep;  // first 32768 bytes: safe under all encodings
        if (m[i]) { int md = i & 3; if (md == 0) l0 = 1; else if (md == 1) l1 = 1; else l23 = 1; }
    }
    if (l0) atomicOr(&flags[0], 1);
    if (l1) atomicOr(&flags[1], 1);
    if (l23) atomicOr(&flags[2], 1);
}

__global__ __launch_bounds__(64) void lengths_kernel(const unsigned char* __restrict__ m,
                                                     const int* __restrict__ flags,
                                                     int* __restrict__ lengths) {
    int b = blockIdx.x, t = threadIdx.x;
    int enc = flags[1] ? 1 : (flags[2] ? 2 : 0);  // 1=uint8, 2=float32, 0=int32
    int cnt = 0;
    for (int s = t; s < Ss; s += 64) {
        int idx = b * Ss + s;
        int mm;
        if (enc == 1)      mm = (m[idx] != 0);
        else if (enc == 2) mm = (((const float*)(const void*)m)[idx] != 0.0f);
        else               mm = (((const int*)(const void*)m)[idx] != 0);
        cnt += (mm == 0);  // monotone mask: zero count == length
    }
    cnt += __shfl_xor(cnt, 1);  cnt += __shfl_xor(cnt, 2);  cnt += __shfl_xor(cnt, 4);
    cnt += __shfl_xor(cnt, 8);  cnt += __shfl_xor(cnt, 16); cnt += __shfl_xor(cnt, 32);
    if (t == 0) lengths[b] = cnt;
}

// ---------------- positional encoding table (S,E) f32 ----------------
__global__ __launch_bounds__(256) void pe_kernel(float* __restrict__ pe) {
    int idx = blockIdx.x * 256 + threadIdx.x;
    if (idx >= Ss * Ee) return;
    int s = idx >> 7, e = idx & 127;
    float expo = (float)(2 * (e >> 1)) * (1.0f / 128.0f);
    float freq = powf(10000.0f, -expo);
    float angle = (float)s * freq;
    pe[idx] = (e & 1) ? cosf(angle) : sinf(angle);
}

// ------------- weight prep: tiled transpose-convert f32 (K,N) -> bf16 (N,K) -------
__global__ __launch_bounds__(256) void wprep_kernel(const float* __restrict__ ew,
                                                    const float* __restrict__ qw,
                                                    const float* __restrict__ ow,
                                                    const float* __restrict__ f1w,
                                                    const float* __restrict__ f2w,
                                                    u16* __restrict__ we, u16* __restrict__ wq,
                                                    u16* __restrict__ wo, u16* __restrict__ wf1,
                                                    u16* __restrict__ wf2) {
    int bid = blockIdx.x;
    const float* src; u16* dst; int K, N, tile;
    if (bid < 32)       { src = ew;  dst = we;  K = 1024; N = 128; tile = bid; }
    else if (bid < 80)  { int b = bid - 32;  int mat = b >> 2; src = qw  + (size_t)mat * 16384; dst = wq  + (size_t)mat * 16384; K = 128; N = 128; tile = b & 3; }
    else if (bid < 96)  { int b = bid - 80;  int mat = b >> 2; src = ow  + (size_t)mat * 16384; dst = wo  + (size_t)mat * 16384; K = 128; N = 128; tile = b & 3; }
    else if (bid < 160) { int b = bid - 96;  int mat = b >> 4; src = f1w + (size_t)mat * 65536; dst = wf1 + (size_t)mat * 65536; K = 128; N = 512; tile = b & 15; }
    else                { int b = bid - 160; int mat = b >> 4; src = f2w + (size_t)mat * 65536; dst = wf2 + (size_t)mat * 65536; K = 512; N = 128; tile = b & 15; }
    int ktiles = K >> 6;
    int k0 = (tile % ktiles) * 64, n0 = (tile / ktiles) * 64;
    __shared__ __align__(16) u16 t_s[64 * 68];
    int r = threadIdx.x >> 2, cq = (threadIdx.x & 3) * 16;
    const float* sp = src + (size_t)(k0 + r) * N + n0 + cq;
#pragma unroll
    for (int i = 0; i < 4; ++i) {
        float4 f = *(const float4*)(sp + 4 * i);
        *(uint2*)&t_s[r * 68 + cq + 4 * i] = pk4(f);
    }
    __syncthreads();
    u16 tmp[16];
#pragma unroll
    for (int kk = 0; kk < 16; ++kk) tmp[kk] = t_s[(cq + kk) * 68 + r];
    u16* dp = dst + (size_t)(n0 + r) * K + k0 + cq;
    *(uint4*)dp       = ((uint4*)tmp)[0];
    *(uint4*)(dp + 8) = ((uint4*)tmp)[1];
}

// ---------------- embed GEMM: h = x(f32) @ wt_embed^T + bias + pe ----------------
__global__ __launch_bounds__(256) void embed_gemm(const float* __restrict__ X,
                                                  const u16* __restrict__ Wt,
                                                  const float* __restrict__ bias,
                                                  const float* __restrict__ pe,
                                                  u16* __restrict__ C) {
    __shared__ __align__(16) u16 Af[64 * 68];
    __shared__ __align__(16) u16 Bs[128 * 64];
    const int tid = threadIdx.x;
    const int w = tid >> 6, lane = tid & 63, l16 = lane & 15, lhi = lane >> 4;
    const int row0 = blockIdx.x * 64;
    f32x4 acc[8];
#pragma unroll
    for (int ni = 0; ni < 8; ++ni) acc[ni] = (f32x4){0.f, 0.f, 0.f, 0.f};

    const int ar = tid >> 2, ak = (tid & 3) * 16;
    const int crow = tid >> 3, cc8 = (tid & 7) * 8;
    const int wave_lds = w * 512;
    const u16* Bbase = Wt + cc8;
    const float* Arow = X + (size_t)(row0 + ar) * 1024 + ak;

    for (int k0 = 0; k0 < 1024; k0 += 64) {
        __syncthreads();
#pragma unroll
        for (int i = 0; i < 4; ++i)
            GLOAD_LDS16(Bbase + (size_t)(i * 32 + crow) * 1024 + k0, &Bs[i * 2048 + wave_lds]);
#pragma unroll
        for (int i = 0; i < 4; ++i) {
            float4 f = *(const float4*)(Arow + k0 + 4 * i);
            *(uint2*)&Af[ar * 68 + ak + 4 * i] = pk4(f);
        }
        __syncthreads();
#pragma unroll
        for (int ks = 0; ks < 2; ++ks) {
            short8 af;
            ((uint2*)&af)[0] = *(const uint2*)&Af[(w * 16 + l16) * 68 + ks * 32 + lhi * 8];
            ((uint2*)&af)[1] = *(const uint2*)&Af[(w * 16 + l16) * 68 + ks * 32 + lhi * 8 + 4];
#pragma unroll
            for (int ni = 0; ni < 8; ++ni) {
                short8 bfr = *(const short8*)&Bs[(ni * 16 + l16) * 64 + ks * 32 + lhi * 8];
                acc[ni] = __builtin_amdgcn_mfma_f32_16x16x32_bf16(af, bfr, acc[ni], 0, 0, 0);
            }
        }
    }
    float biasr[8];
#pragma unroll
    for (int ni = 0; ni < 8; ++ni) biasr[ni] = bias[ni * 16 + l16];
#pragma unroll
    for (int reg = 0; reg < 4; ++reg) {
        int r = row0 + w * 16 + lhi * 4 + reg;
        const float* per = pe + (size_t)(r & 511) * 128;
        u16* crw = C + (size_t)r * 128;
#pragma unroll
        for (int ni = 0; ni < 8; ++ni) {
            int c = ni * 16 + l16;
            crw[c] = f2b(acc[ni][reg] + biasr[ni] + per[c]);
        }
    }
}

// ---------------- QKV GEMM: single-shot K=128, BM=128, N-tile 128 ----------------
// rows permuted r=b*S+s -> s*64+b; split: y=0 -> Q (ld 128), y=1,2 -> KV (ld 256)
__global__ __launch_bounds__(256) void qkv_gemm(const u16* __restrict__ A,
                                                const u16* __restrict__ Wt,
                                                const float* __restrict__ bias,
                                                u16* __restrict__ Cq,
                                                u16* __restrict__ Ckv) {
    __shared__ __align__(16) u16 As[128 * 128];
    __shared__ __align__(16) u16 Bs[128 * 128];
    const int tid = threadIdx.x, w = tid >> 6, lane = tid & 63;
    const int l16 = lane & 15, lhi = lane >> 4;
    const int row0 = blockIdx.x * 128, col0 = blockIdx.y * 128;
    const int so = w * 512 + lane * 8;
#pragma unroll
    for (int i = 0; i < 8; ++i) {
        GLOAD_LDS16(A + (size_t)row0 * 128 + i * 2048 + so, &As[i * 2048 + w * 512]);
        GLOAD_LDS16(Wt + (size_t)col0 * 128 + i * 2048 + so, &Bs[i * 2048 + w * 512]);
    }
    __syncthreads();
    f32x4 acc[2][8];
#pragma unroll
    for (int mi = 0; mi < 2; ++mi)
#pragma unroll
        for (int ni = 0; ni < 8; ++ni) acc[mi][ni] = (f32x4){0.f, 0.f, 0.f, 0.f};
#pragma unroll
    for (int ks = 0; ks < 4; ++ks) {
        short8 af[2], bfr[8];
#pragma unroll
        for (int mi = 0; mi < 2; ++mi)
            af[mi] = *(const short8*)&As[(w * 32 + mi * 16 + l16) * 128 + ks * 32 + lhi * 8];
#pragma unroll
        for (int ni = 0; ni < 8; ++ni)
            bfr[ni] = *(const short8*)&Bs[(ni * 16 + l16) * 128 + ks * 32 + lhi * 8];
#pragma unroll
        for (int mi = 0; mi < 2; ++mi)
#pragma unroll
            for (int ni = 0; ni < 8; ++ni)
                acc[mi][ni] = __builtin_amdgcn_mfma_f32_16x16x32_bf16(af[mi], bfr[ni], acc[mi][ni], 0, 0, 0);
    }
    float biasr[8];
#pragma unroll
    for (int ni = 0; ni < 8; ++ni) biasr[ni] = bias[col0 + ni * 16 + l16];
#pragma unroll
    for (int mi = 0; mi < 2; ++mi)
#pragma unroll
        for (int reg = 0; reg < 4; ++reg) {
            int r = row0 + w * 32 + mi * 16 + lhi * 4 + reg;
            int orow = ((r & 511) << 6) + (r >> 9);
            u16* crw; int cbase;
            if (col0 == 0) { crw = Cq + (size_t)orow * 128; cbase = 0; }
            else           { crw = Ckv + (size_t)orow * 256; cbase = col0 - 128; }
#pragma unroll
            for (int ni = 0; ni < 8; ++ni)
                crw[cbase + ni * 16 + l16] = f2b(acc[mi][ni][reg] + biasr[ni]);
        }
}

// ------- MFMA attention + out-proj + residual + LN, one block per s ----------
__global__ __launch_bounds__(256) void attnout_kernel(const u16* __restrict__ qb,
                                                      const u16* __restrict__ kvb,
                                                      const u16* __restrict__ wo,
                                                      const float* __restrict__ outb,
                                                      const int* __restrict__ lengths,
                                                      const float* __restrict__ gamma,
                                                      const float* __restrict__ beta,
                                                      u16* __restrict__ h) {
    const int s = blockIdx.x;
    const int tid = threadIdx.x, w = tid >> 6, lane = tid & 63;
    const int l16 = lane & 15, lhi = lane >> 4;
    __shared__ __align__(16) u16 Vt[8 * 16 * 72];   // V transposed [h][d][j], pad 72
    __shared__ __align__(16) u16 Ps[4 * 64 * 72];   // per-wave P [i][j], pad 72
    __shared__ __align__(16) u16 o_s[64 * 136];     // attention output [i][e], pad 136
    __shared__ int len_s[64];

    {   // stage V transposed: thread t reads row j = t>>2, heads 2c,2c+1
        int j = tid >> 2, c = tid & 3;
        const u16* src = kvb + ((size_t)(s * 64 + j)) * 256 + 128 + c * 32;
        u16 tmp[32];
        ((uint4*)tmp)[0] = *(const uint4*)src;
        ((uint4*)tmp)[1] = *(const uint4*)(src + 8);
        ((uint4*)tmp)[2] = *(const uint4*)(src + 16);
        ((uint4*)tmp)[3] = *(const uint4*)(src + 24);
#pragma unroll
        for (int e = 0; e < 32; ++e) {
            int hh = 2 * c + (e >> 4), d = e & 15;
            Vt[hh * 1152 + d * 72 + j] = tmp[e];
        }
    }
    if (tid < 64) len_s[tid] = lengths[tid];
    __syncthreads();

    bool mk[4];
#pragma unroll
    for (int jt = 0; jt < 4; ++jt) mk[jt] = (s >= len_s[jt * 16 + l16]);

    u16* pw = Ps + w * 4608;
#pragma unroll
    for (int hp = 0; hp < 2; ++hp) {
        const int hh = w * 2 + hp;
        // ---- QK^T: head dim 16 zero-padded to k=32 via conditional frag loads ----
        short8 af[4];
#pragma unroll
        for (int it = 0; it < 4; ++it) {
            af[it] = (short8){0, 0, 0, 0, 0, 0, 0, 0};
            if (lhi < 2)
                af[it] = *(const short8*)(qb + ((size_t)(s * 64 + it * 16 + l16)) * 128 + hh * 16 + lhi * 8);
        }
        f32x4 sf[4][4];
#pragma unroll
        for (int jt = 0; jt < 4; ++jt) {
            short8 bf = (short8){0, 0, 0, 0, 0, 0, 0, 0};
            if (lhi < 2)
                bf = *(const short8*)(kvb + ((size_t)(s * 64 + jt * 16 + l16)) * 256 + hh * 16 + lhi * 8);
#pragma unroll
            for (int it = 0; it < 4; ++it)
                sf[it][jt] = __builtin_amdgcn_mfma_f32_16x16x32_bf16(af[it], bf, (f32x4){0.f, 0.f, 0.f, 0.f}, 0, 0, 0);
        }
        // ---- softmax (rows across l16 lanes + 4 jt frags), P unnormalized ----
        float inv[4][4];
#pragma unroll
        for (int it = 0; it < 4; ++it) {
#pragma unroll
            for (int reg = 0; reg < 4; ++reg) {
                float vv[4], mx = -1e30f;
#pragma unroll
                for (int jt = 0; jt < 4; ++jt) {
                    float xv = mk[jt] ? -1e30f : sf[it][jt][reg] * 0.25f;
                    vv[jt] = xv; mx = fmaxf(mx, xv);
                }
                mx = fmaxf(mx, __shfl_xor(mx, 1)); mx = fmaxf(mx, __shfl_xor(mx, 2));
                mx = fmaxf(mx, __shfl_xor(mx, 4)); mx = fmaxf(mx, __shfl_xor(mx, 8));
                float e4[4], sum = 0.f;
#pragma unroll
                for (int jt = 0; jt < 4; ++jt) {
                    float e = mk[jt] ? 0.f : __expf(vv[jt] - mx);
                    e4[jt] = e; sum += e;
                }
                sum += __shfl_xor(sum, 1); sum += __shfl_xor(sum, 2);
                sum += __shfl_xor(sum, 4); sum += __shfl_xor(sum, 8);
                inv[it][reg] = 1.0f / sum;
                int prow = it * 16 + lhi * 4 + reg;
#pragma unroll
                for (int jt = 0; jt < 4; ++jt)
                    pw[prow * 72 + jt * 16 + l16] = f2b(e4[jt]);
            }
        }
        // ---- PV: P(64x64) @ V(64x16), k=64 in 2 steps; scale by inv at O-write ----
        f32x4 ao[4];
#pragma unroll
        for (int it = 0; it < 4; ++it) ao[it] = (f32x4){0.f, 0.f, 0.f, 0.f};
        short8 vb[2];
#pragma unroll
        for (int ksv = 0; ksv < 2; ++ksv)
            vb[ksv] = *(const short8*)&Vt[hh * 1152 + l16 * 72 + ksv * 32 + lhi * 8];
#pragma unroll
        for (int it = 0; it < 4; ++it)
#pragma unroll
            for (int ksv = 0; ksv < 2; ++ksv) {
                short8 pa = *(const short8*)&pw[(it * 16 + l16) * 72 + ksv * 32 + lhi * 8];
                ao[it] = __builtin_amdgcn_mfma_f32_16x16x32_bf16(pa, vb[ksv], ao[it], 0, 0, 0);
            }
#pragma unroll
        for (int it = 0; it < 4; ++it)
#pragma unroll
            for (int reg = 0; reg < 4; ++reg)
                o_s[(it * 16 + lhi * 4 + reg) * 136 + hh * 16 + l16] = f2b(ao[it][reg] * inv[it][reg]);
    }
    __syncthreads();

    // ---- out-proj: o(64x128) @ wo^T + bias + residual + LN ----
    f32x4 acc[8];
#pragma unroll
    for (int ni = 0; ni < 8; ++ni) acc[ni] = (f32x4){0.f, 0.f, 0.f, 0.f};
#pragma unroll
    for (int ks = 0; ks < 4; ++ks) {
        short8 af = *(const short8*)&o_s[(w * 16 + l16) * 136 + ks * 32 + lhi * 8];
#pragma unroll
        for (int ni = 0; ni < 8; ++ni) {
            short8 bf = *(const short8*)(wo + (size_t)(ni * 16 + l16) * 128 + ks * 32 + lhi * 8);
            acc[ni] = __builtin_amdgcn_mfma_f32_16x16x32_bf16(af, bf, acc[ni], 0, 0, 0);
        }
    }
    float biasr[8], gr[8], br[8];
#pragma unroll
    for (int ni = 0; ni < 8; ++ni) {
        int c = ni * 16 + l16;
        biasr[ni] = outb[c]; gr[ni] = gamma[c]; br[ni] = beta[c];
    }
#pragma unroll
    for (int reg = 0; reg < 4; ++reg) {
        int b = w * 16 + lhi * 4 + reg;
        size_t rbase = ((size_t)b * 512 + s) * 128;
        float v[8], sm = 0.f, s2 = 0.f;
#pragma unroll
        for (int ni = 0; ni < 8; ++ni) {
            float x = acc[ni][reg] + biasr[ni] + b2f(h[rbase + ni * 16 + l16]);
            v[ni] = x; sm += x; s2 += x * x;
        }
        sm += __shfl_xor(sm, 1); sm += __shfl_xor(sm, 2);
        sm += __shfl_xor(sm, 4); sm += __shfl_xor(sm, 8);
        s2 += __shfl_xor(s2, 1); s2 += __shfl_xor(s2, 2);
        s2 += __shfl_xor(s2, 4); s2 += __shfl_xor(s2, 8);
        float mean = sm * (1.0f / 128.0f);
        float var = s2 * (1.0f / 128.0f) - mean * mean;
        float rstd = rsqrtf(fmaxf(var, 0.0f) + 1e-5f);
#pragma unroll
        for (int ni = 0; ni < 8; ++ni)
            h[rbase + ni * 16 + l16] = f2b((v[ni] - mean) * rstd * gr[ni] + br[ni]);
    }
}

// ---------- fused FF: h = LN(relu(h@W1+b1)@W2 + b2 + h) (+pe), BM=128 ----------
__global__ __launch_bounds__(256) void ff_fused(const u16* __restrict__ hbuf,
                                                const u16* __restrict__ w1t,
                                                const u16* __restrict__ w2t,
                                                const float* __restrict__ b1,
                                                const float* __restrict__ b2,
                                                const float* __restrict__ gamma,
                                                const float* __restrict__ beta,
                                                const float* __restrict__ pe,
                                                u16* __restrict__ hout) {
    __shared__ __align__(16) u16 A_s[16384];
    __shared__ __align__(16) u16 W1_s[16384];
    __shared__ __align__(16) u16 W2_s[16384];
    __shared__ __align__(16) u16 T_s[16384];
    const int tid = threadIdx.x, w = tid >> 6, lane = tid & 63;
    const int l16 = lane & 15, lhi = lane >> 4;
    const int row0 = blockIdx.x * 128;
    const int so = w * 512 + lane * 8;
#pragma unroll
    for (int i = 0; i < 8; ++i)
        GLOAD_LDS16(hbuf + (size_t)row0 * 128 + i * 2048 + so, &A_s[i * 2048 + w * 512]);

    f32x4 acc2[2][8];
#pragma unroll
    for (int mi = 0; mi < 2; ++mi)
#pragma unroll
        for (int ni = 0; ni < 8; ++ni) acc2[mi][ni] = (f32x4){0.f, 0.f, 0.f, 0.f};

    for (int nc = 0; nc < 4; ++nc) {
        __syncthreads();   // prior readers of W1_s/W2_s done (also drains A stage at nc=0)
#pragma unroll
        for (int i = 0; i < 8; ++i) {
            GLOAD_LDS16(w1t + nc * 16384 + i * 2048 + so, &W1_s[i * 2048 + w * 512]);
            int slot = i * 2048 + so;
            GLOAD_LDS16(w2t + (size_t)(slot >> 7) * 512 + nc * 128 + (slot & 127),
                        &W2_s[i * 2048 + w * 512]);
        }
        __syncthreads();
        // FF1: t = relu(A @ W1c^T + b1c)
        f32x4 acc1[2][8];
#pragma unroll
        for (int mi = 0; mi < 2; ++mi)
#pragma unroll
            for (int ni = 0; ni < 8; ++ni) acc1[mi][ni] = (f32x4){0.f, 0.f, 0.f, 0.f};
#pragma unroll
        for (int ks = 0; ks < 4; ++ks) {
            short8 af[2], bfr[8];
#pragma unroll
            for (int mi = 0; mi < 2; ++mi)
                af[mi] = *(const short8*)&A_s[(w * 32 + mi * 16 + l16) * 128 + ks * 32 + lhi * 8];
#pragma unroll
            for (int ni = 0; ni < 8; ++ni)
                bfr[ni] = *(const short8*)&W1_s[(ni * 16 + l16) * 128 + ks * 32 + lhi * 8];
#pragma unroll
            for (int mi = 0; mi < 2; ++mi)
#pragma unroll
                for (int ni = 0; ni < 8; ++ni)
                    acc1[mi][ni] = __builtin_amdgcn_mfma_f32_16x16x32_bf16(af[mi], bfr[ni], acc1[mi][ni], 0, 0, 0);
        }
        float bb[8];
#pragma unroll
        for (int ni = 0; ni < 8; ++ni) bb[ni] = b1[nc * 128 + ni * 16 + l16];
#pragma unroll
        for (int mi = 0; mi < 2; ++mi)
#pragma unroll
            for (int reg = 0; reg < 4; ++reg)
#pragma unroll
                for (int ni = 0; ni < 8; ++ni)
                    T_s[(w * 32 + mi * 16 + lhi * 4 + reg) * 128 + ni * 16 + l16] =
                        f2b(fmaxf(acc1[mi][ni][reg] + bb[ni], 0.0f));
        // T rows are wave-local (written and read only by this wave): no barrier
#pragma unroll
        for (int ks = 0; ks < 4; ++ks) {
            short8 pa[2], bfr[8];
#pragma unroll
            for (int mi = 0; mi < 2; ++mi)
                pa[mi] = *(const short8*)&T_s[(w * 32 + mi * 16 + l16) * 128 + ks * 32 + lhi * 8];
#pragma unroll
            for (int ni = 0; ni < 8; ++ni)
                bfr[ni] = *(const short8*)&W2_s[(ni * 16 + l16) * 128 + ks * 32 + lhi * 8];
#pragma unroll
            for (int mi = 0; mi < 2; ++mi)
#pragma unroll
                for (int ni = 0; ni < 8; ++ni)
                    acc2[mi][ni] = __builtin_amdgcn_mfma_f32_16x16x32_bf16(pa[mi], bfr[ni], acc2[mi][ni], 0, 0, 0);
        }
    }
    // epilogue: + b2 + residual(A_s) + LN (+pe)
    float b2r[8], gr[8], br[8];
#pragma unroll
    for (int ni = 0; ni < 8; ++ni) {
        int c = ni * 16 + l16;
        b2r[ni] = b2[c]; gr[ni] = gamma[c]; br[ni] = beta[c];
    }
#pragma unroll
    for (int mi = 0; mi < 2; ++mi)
#pragma unroll
        for (int reg = 0; reg < 4; ++reg) {
            int lrow = w * 32 + mi * 16 + lhi * 4 + reg;
            int r = row0 + lrow;
            float v[8], sm = 0.f, s2 = 0.f;
#pragma unroll
            for (int ni = 0; ni < 8; ++ni) {
                float x = acc2[mi][ni][reg] + b2r[ni] + b2f(A_s[lrow * 128 + ni * 16 + l16]);
                v[ni] = x; sm += x; s2 += x * x;
            }
            sm += __shfl_xor(sm, 1); sm += __shfl_xor(sm, 2);
            sm += __shfl_xor(sm, 4); sm += __shfl_xor(sm, 8);
            s2 += __shfl_xor(s2, 1); s2 += __shfl_xor(s2, 2);
            s2 += __shfl_xor(s2, 4); s2 += __shfl_xor(s2, 8);
            float mean = sm * (1.0f / 128.0f);
            float var = s2 * (1.0f / 128.0f) - mean * mean;
            float rstd = rsqrtf(fmaxf(var, 0.0f) + 1e-5f);
            u16* crw = hout + (size_t)r * 128;
#pragma unroll
            for (int ni = 0; ni < 8; ++ni) {
                int c = ni * 16 + l16;
                float val = (v[ni] - mean) * rstd * gr[ni] + br[ni];
                if (pe) val += pe[(size_t)(r & 511) * 128 + c];
                crw[c] = f2b(val);
            }
        }
}

// ---------------- masked mean pool (bf16 h -> f32 meanp) ----------------
__global__ __launch_bounds__(256) void pool_kernel(const u16* __restrict__ h,
                                                   const int* __restrict__ lengths,
                                                   float* __restrict__ meanp) {
    int b = blockIdx.x, e = threadIdx.x & 127, q = threadIdx.x >> 7;
    int len = lengths[b];
    float s = 0.0f;
    for (int t = q; t < len; t += 2) s += b2f(h[((size_t)b * Ss + t) * Ee + e]);
    __shared__ float red[256];
    red[threadIdx.x] = s;
    __syncthreads();
    if (threadIdx.x < 128)
        meanp[b * Ee + threadIdx.x] = (red[threadIdx.x] + red[threadIdx.x + 128]) / (float)len;
}

// ---------------- classifier head ----------------
__global__ __launch_bounds__(64) void head_kernel(const float* __restrict__ meanp,
                                                  const float* __restrict__ fc1w,
                                                  const float* __restrict__ fc1b,
                                                  const float* __restrict__ fc2w,
                                                  const float* __restrict__ fc2b,
                                                  float* __restrict__ out) {
    int b = blockIdx.x, j = threadIdx.x;
    __shared__ float z[32];
    if (j < 32) {
        float a = fc1b[j];
        for (int e = 0; e < 128; ++e) a = fmaf(meanp[b * 128 + e], fc1w[e * 32 + j], a);
        z[j] = fmaxf(a, 0.0f);
    }
    __syncthreads();
    if (j == 0) {
        float a = fc2b[0];
#pragma unroll
        for (int t = 0; t < 32; ++t) a = fmaf(z[t], fc2w[t], a);
        out[b] = 1.0f / (1.0f + expf(-a));
    }
}

extern "C" void kernel_launch(void* const* d_in, const int* in_sizes, int n_in,
                              void* d_out, int out_size, void* d_ws, size_t ws_size,
                              hipStream_t stream) {
    (void)in_sizes; (void)n_in; (void)out_size; (void)ws_size;
    const float* x        = (const float*)d_in[0];
    const unsigned char* mask = (const unsigned char*)d_in[1];
    const float* embed_w  = (const float*)d_in[2];
    const float* embed_b  = (const float*)d_in[3];
    const float* qkv_w    = (const float*)d_in[4];
    const float* qkv_b    = (const float*)d_in[5];
    const float* out_w    = (const float*)d_in[6];
    const float* out_b    = (const float*)d_in[7];
    const float* ln_g     = (const float*)d_in[8];
    const float* ln_b     = (const float*)d_in[9];
    const float* ff1_w    = (const float*)d_in[10];
    const float* ff1_b    = (const float*)d_in[11];
    const float* ff2_w    = (const float*)d_in[12];
    const float* ff2_b    = (const float*)d_in[13];
    const float* fc1_w    = (const float*)d_in[14];
    const float* fc1_b    = (const float*)d_in[15];
    const float* fc2_w    = (const float*)d_in[16];
    const float* fc2_b    = (const float*)d_in[17];

    char* wsb = (char*)d_ws;
    int*   lengths = (int*)wsb;                  // 256 B
    int*   flags   = (int*)(wsb + 256);          // 256 B
    float* pe      = (float*)(wsb + 512);        // 256 KiB -> 262656
    u16* wt_embed  = (u16*)(wsb + 262656);       // 256 KiB -> 524800
    u16* wt_qkv    = (u16*)(wsb + 524800);       // 384 KiB -> 918016
    u16* wt_out    = (u16*)(wsb + 918016);       // 128 KiB -> 1049088
    u16* wt_ff1    = (u16*)(wsb + 1049088);      // 512 KiB -> 1573376
    u16* wt_ff2    = (u16*)(wsb + 1573376);      // 512 KiB -> 2097664
    u16* hbuf      = (u16*)(wsb + 2097664);      // 8 MiB  -> 10486272
    u16* qb        = (u16*)(wsb + 10486272);     // 8 MiB  -> 18874880
    u16* kvb       = (u16*)(wsb + 18874880);     // 16 MiB -> 35652096
    float* meanp   = (float*)(wsb + 35652096);   // 32 KiB

    hipMemsetAsync(flags, 0, 12, stream);
    detect_kernel<<<8, 256, 0, stream>>>(mask, flags);
    lengths_kernel<<<64, 64, 0, stream>>>(mask, flags, lengths);
    pe_kernel<<<256, 256, 0, stream>>>(pe);
    wprep_kernel<<<224, 256, 0, stream>>>(embed_w, qkv_w, out_w, ff1_w, ff2_w,
                                          wt_embed, wt_qkv, wt_out, wt_ff1, wt_ff2);

    // embed: h = x @ embed_w + b + pe   (B,S) rows
    embed_gemm<<<512, 256, 0, stream>>>(x, wt_embed, embed_b, pe, hbuf);

    for (int l = 0; l < NLl; ++l) {
        qkv_gemm<<<dim3(256, 3), 256, 0, stream>>>(
            hbuf, wt_qkv + (size_t)l * 49152, qkv_b + l * 384, qb, kvb);
        attnout_kernel<<<512, 256, 0, stream>>>(
            qb, kvb, wt_out + (size_t)l * 16384, out_b + l * 128,
            lengths, ln_g + l * 128, ln_b + l * 128, hbuf);
        ff_fused<<<256, 256, 0, stream>>>(
            hbuf, wt_ff1 + (size_t)l * 65536, wt_ff2 + (size_t)l * 65536,
            ff1_b + l * 512, ff2_b + l * 128,
            ln_g + l * 128, ln_b + l * 128, (l < 3) ? pe : nullptr, hbuf);
    }

    pool_kernel<<<64, 256, 0, stream>>>(hbuf, lengths, meanp);
    head_kernel<<<64, 64, 0, stream>>>(meanp, fc1_w, fc1_b, fc2_w, fc2_b, (float*)d_out);
}